// Round 8
// baseline (863.820 us; speedup 1.0000x reference)
//
#include <hip/hip_runtime.h>
#include <hip/hip_fp16.h>
#include <math.h>

#define NN 100000
#define NE 3200000
#define NG 1024
#define FDIM 128
#define NFC1 64
#define NFC2 10

#define BSHIFT 9
#define NBUCK 196   // ceil(NN/512)
#define CAP 20480   // mean 16384, sigma ~127 -> 32-sigma headroom
#define EPB 16      // edges per thread in bin_kernel

#define RF __builtin_amdgcn_readfirstlane
// quarter-select: quarter q of the wave takes value k_q (static indices only)
#define QSEL(q, v0, v1, v2, v3) ((q) == 0 ? (v0) : (q) == 1 ? (v1) : (q) == 2 ? (v2) : (v3))

// ---------------- pass 1: bin edges into 196 coarse buckets ----------------
// Packed value: (dst & 511) << 17 | src   (src < 2^17, dst_local < 2^9)
__global__ __launch_bounds__(256) void bin_kernel(const int* __restrict__ src,
                                                  const int* __restrict__ dst,
                                                  int* __restrict__ gcursor,
                                                  int* __restrict__ staging) {
  __shared__ int hist[NBUCK];
  __shared__ int base[NBUCK];
  int t = threadIdx.x;
  for (int i = t; i < NBUCK; i += 256) hist[i] = 0;
  __syncthreads();
  size_t e0 = (size_t)blockIdx.x * (256 * EPB);
  int bk[EPB], rank[EPB], val[EPB];
#pragma unroll
  for (int j = 0; j < EPB; ++j) {
    size_t e = e0 + (size_t)j * 256 + t;
    if (e < NE) {
      int d = dst[e];
      int s = src[e];
      bk[j] = d >> BSHIFT;
      val[j] = ((d & 511) << 17) | s;
      rank[j] = atomicAdd(&hist[bk[j]], 1);
    } else {
      bk[j] = -1;
    }
  }
  __syncthreads();
  for (int i = t; i < NBUCK; i += 256) base[i] = atomicAdd(&gcursor[i], hist[i]);
  __syncthreads();
#pragma unroll
  for (int j = 0; j < EPB; ++j) {
    if (bk[j] >= 0) {
      int pos = base[bk[j]] + rank[j];
      if (pos < CAP) staging[(size_t)bk[j] * CAP + pos] = val[j];
    }
  }
}

// ---------------- pass 2: per-bucket CSR finalize (scan fused in) ----------------
__global__ __launch_bounds__(256) void build_kernel(const int* __restrict__ staging,
                                                    const int* __restrict__ gcursor,
                                                    int* __restrict__ row_off,
                                                    int* __restrict__ esrc) {
  __shared__ int ncnt[512];
  __shared__ int noff[513];
  __shared__ int part[256];
  __shared__ int sscan[256];
  int b = blockIdx.x, t = threadIdx.x;
  int gv = (t < NBUCK) ? gcursor[t] : 0;
  sscan[t] = gv;
  __syncthreads();
  for (int st = 1; st < 256; st <<= 1) {
    int u = (t >= st) ? sscan[t - st] : 0;
    __syncthreads();
    sscan[t] += u;
    __syncthreads();
  }
  int cnt = gcursor[b];
  int ebase = sscan[b] - cnt;  // exclusive prefix
  int nbase = b << BSHIFT;
  ncnt[t] = 0;
  ncnt[t + 256] = 0;
  __syncthreads();
  const int* sp = staging + (size_t)b * CAP;
  for (int i = t; i < cnt; i += 256) {
    int dl = sp[i] >> 17;
    atomicAdd(&ncnt[dl], 1);
  }
  __syncthreads();
  int a0 = ncnt[2 * t], a1 = ncnt[2 * t + 1];
  part[t] = a0 + a1;
  __syncthreads();
  for (int st = 1; st < 256; st <<= 1) {
    int u = (t >= st) ? part[t - st] : 0;
    __syncthreads();
    part[t] += u;
    __syncthreads();
  }
  int excl = (t > 0) ? part[t - 1] : 0;
  noff[2 * t] = excl;
  noff[2 * t + 1] = excl + a0;
  if (t == 255) noff[512] = part[255];
  __syncthreads();
  for (int i = t; i <= 512; i += 256) {
    int n = nbase + i;
    if (n <= NN) row_off[n] = ebase + noff[i];
  }
  // reuse ncnt as write cursors
  ncnt[2 * t] = noff[2 * t];
  ncnt[2 * t + 1] = noff[2 * t + 1];
  __syncthreads();
  for (int i = t; i < cnt; i += 256) {
    int v = sp[i];
    int dl = v >> 17;
    int pos = atomicAdd(&ncnt[dl], 1);
    esrc[ebase + pos] = v & 0x1FFFF;
  }
}

// ---------------- fp32 -> fp16 convert (node_attr -> xh0) ----------------
__global__ __launch_bounds__(256) void cvt_kernel(const float4* __restrict__ in,
                                                  uint2* __restrict__ outp, int n) {
  int i = blockIdx.x * 256 + threadIdx.x;
  int stride = gridDim.x * 256;
  for (; i < n; i += stride) {
    float4 v = in[i];
    union { __half2 h; unsigned u; } u0, u1;
    u0.h = __float22half2_rn(make_float2(v.x, v.y));
    u1.h = __float22half2_rn(make_float2(v.z, v.w));
    outp[i] = make_uint2(u0.u, u1.u);
  }
}

// ---------------- fused conv layer: out = relu(gather(xh)@W + bias) -------
// Gather path is fp16 (row = 128 half = 256B); ALL arithmetic fp32.
// 512 threads = 8 waves; 64 dst nodes/block. Quad-edge gather: wave quarter
// q (16 lanes) reads edge e+q of each quad; lane chunk c (lane&15) reads
// 16B = 8 halfs. MAIN LOOP (changed this round): 32 edges/iter = 8 quads =
// 8 dwordx4 in flight = 128 B/lane (R6's proven MLP depth on half the
// bytes; R7's 4-in-flight was latency-bound at 1.54 TB/s). Cross-quarter
// combine via shfl_xor(16)+shfl_xor(32); transposed LDS store; fp32 64x128
// GEMM (4x4 acc/thread, W from L1). POOL=0: fp16 output store.
// POOL=1 (layer 3): fp32 global_sum_pool epilogue, no x write.
template <int POOL>
__global__ __launch_bounds__(512) void conv_fused(const float4* __restrict__ xh4,
                                                  const int* __restrict__ row_off,
                                                  const int* __restrict__ esrc,
                                                  const float* __restrict__ W,
                                                  const float* __restrict__ bias,
                                                  const int* __restrict__ batching,
                                                  __half* __restrict__ out,
                                                  float* __restrict__ gout) {
  __shared__ __align__(16) float aT[128 * 68];
  __shared__ float gl[8 * FDIM];
  __shared__ int sgv[2];
  int t = threadIdx.x;
  int w = t >> 6;
  int lane = t & 63;
  int q = lane >> 4;   // edge within quad
  int c = lane & 15;   // 16B chunk within the 256B fp16 row
  int nodebase = blockIdx.x * 64;

#define CVTACC(fv)                                         \
  {                                                        \
    union { float4 f; __half2 h[4]; } u_;                  \
    u_.f = (fv);                                           \
    float2 p_;                                             \
    p_ = __half22float2(u_.h[0]); a[0] += p_.x; a[1] += p_.y; \
    p_ = __half22float2(u_.h[1]); a[2] += p_.x; a[3] += p_.y; \
    p_ = __half22float2(u_.h[2]); a[4] += p_.x; a[5] += p_.y; \
    p_ = __half22float2(u_.h[3]); a[6] += p_.x; a[7] += p_.y; \
  }

  // ---- phase 1: gather-aggregate 8 nodes for this wave ----
  for (int i = 0; i < 8; ++i) {
    int r = w * 8 + i;
    int node = nodebase + r;
    int beg = 0, end = 0;
    if (node < NN) {
      beg = RF(row_off[node]);
      end = RF(row_off[node + 1]);
    }
    float a[8] = {0.f, 0.f, 0.f, 0.f, 0.f, 0.f, 0.f, 0.f};
    int e = beg;
    // main: 32 edges / iter (8 quads, 8 x dwordx4 = 128B/lane in flight)
    for (; e + 32 <= end; e += 32) {
      int idx[8];
#pragma unroll
      for (int g = 0; g < 8; ++g) {
        int s0 = RF(esrc[e + 4 * g + 0]);
        int s1 = RF(esrc[e + 4 * g + 1]);
        int s2 = RF(esrc[e + 4 * g + 2]);
        int s3 = RF(esrc[e + 4 * g + 3]);
        idx[g] = QSEL(q, s0, s1, s2, s3);
      }
      float4 f[8];
#pragma unroll
      for (int g = 0; g < 8; ++g) f[g] = xh4[(size_t)idx[g] * 16 + c];
#pragma unroll
      for (int g = 0; g < 8; ++g) CVTACC(f[g]);
    }
    // mid: 16 edges / iter (4 quads)
    for (; e + 16 <= end; e += 16) {
      int idx[4];
#pragma unroll
      for (int g = 0; g < 4; ++g) {
        int s0 = RF(esrc[e + 4 * g + 0]);
        int s1 = RF(esrc[e + 4 * g + 1]);
        int s2 = RF(esrc[e + 4 * g + 2]);
        int s3 = RF(esrc[e + 4 * g + 3]);
        idx[g] = QSEL(q, s0, s1, s2, s3);
      }
      float4 f[4];
#pragma unroll
      for (int g = 0; g < 4; ++g) f[g] = xh4[(size_t)idx[g] * 16 + c];
#pragma unroll
      for (int g = 0; g < 4; ++g) CVTACC(f[g]);
    }
    // small: 8 edges / iter (2 quads)
    for (; e + 8 <= end; e += 8) {
      int a0 = RF(esrc[e + 0]), a1 = RF(esrc[e + 1]), a2 = RF(esrc[e + 2]), a3 = RF(esrc[e + 3]);
      int b0 = RF(esrc[e + 4]), b1 = RF(esrc[e + 5]), b2 = RF(esrc[e + 6]), b3 = RF(esrc[e + 7]);
      int iA = QSEL(q, a0, a1, a2, a3);
      int iB = QSEL(q, b0, b1, b2, b3);
      float4 fA = xh4[(size_t)iA * 16 + c];
      float4 fB = xh4[(size_t)iB * 16 + c];
      CVTACC(fA)
      CVTACC(fB)
    }
    // final: predicated quad (esrc padded +8 ints, so scalar reads stay in-bounds;
    // lanes with e+q >= end skip the vector load, so garbage indices are never used)
    for (; e < end; e += 4) {
      int a0 = RF(esrc[e + 0]), a1 = RF(esrc[e + 1]), a2 = RF(esrc[e + 2]), a3 = RF(esrc[e + 3]);
      int iA = QSEL(q, a0, a1, a2, a3);
      float4 fA = make_float4(0.f, 0.f, 0.f, 0.f);
      if (e + q < end) fA = xh4[(size_t)iA * 16 + c];
      CVTACC(fA)
    }
    // combine quarters: lanes {c, c+16, c+32, c+48} hold partials of chunk c
#pragma unroll
    for (int j = 0; j < 8; ++j) {
      a[j] += __shfl_xor(a[j], 16);
      a[j] += __shfl_xor(a[j], 32);
    }
    // transposed store: feature f = c*8 + j; this lane writes j = 2q, 2q+1
    float w0 = QSEL(q, a[0], a[2], a[4], a[6]);
    float w1 = QSEL(q, a[1], a[3], a[5], a[7]);
    aT[(c * 8 + 2 * q + 0) * 68 + r] = w0;
    aT[(c * 8 + 2 * q + 1) * 68 + r] = w1;
  }
  __syncthreads();

  // ---- phase 2: GEMM 64x128 tile (fp32) ----
  int rg = lane >> 5;       // 0..1
  int cc = lane & 31;       // cols 4cc..4cc+3
  int rbase = w * 8 + rg * 4;

  float acc[4][4];
#pragma unroll
  for (int r = 0; r < 4; ++r)
#pragma unroll
    for (int j = 0; j < 4; ++j) acc[r][j] = 0.f;

#pragma unroll 4
  for (int k = 0; k < 128; ++k) {
    float4 bv = *(const float4*)(W + k * FDIM + cc * 4);
    float4 a0 = *(const float4*)(&aT[k * 68 + rbase]);
    float ar[4] = {a0.x, a0.y, a0.z, a0.w};
#pragma unroll
    for (int r = 0; r < 4; ++r) {
      acc[r][0] += ar[r] * bv.x;
      acc[r][1] += ar[r] * bv.y;
      acc[r][2] += ar[r] * bv.z;
      acc[r][3] += ar[r] * bv.w;
    }
  }

  float4 b4 = *(const float4*)(bias + cc * 4);

  if (POOL == 0) {
#pragma unroll
    for (int r = 0; r < 4; ++r) {
      int row = nodebase + rbase + r;
      if (row < NN) {
        float ox = fmaxf(acc[r][0] + b4.x, 0.f);
        float oy = fmaxf(acc[r][1] + b4.y, 0.f);
        float oz = fmaxf(acc[r][2] + b4.z, 0.f);
        float ow = fmaxf(acc[r][3] + b4.w, 0.f);
        union { uint2 u2; __half2 h[2]; } pk;
        pk.h[0] = __float22half2_rn(make_float2(ox, oy));
        pk.h[1] = __float22half2_rn(make_float2(oz, ow));
        *(uint2*)(out + (size_t)row * FDIM + cc * 4) = pk.u2;
      }
    }
  } else {
    // fused global_sum_pool (fp32): batching sorted, 64-row tile spans ~2-3
    // graphs; LDS slots + one global atomic per (graph, feature).
    if (t == 0) {
      sgv[0] = batching[nodebase];
      int last = nodebase + 63;
      if (last >= NN) last = NN - 1;
      sgv[1] = batching[last] - sgv[0] + 1;
    }
    for (int i = t; i < 8 * FDIM; i += 512) gl[i] = 0.f;
    __syncthreads();
    int g0 = sgv[0], nG = sgv[1];
    if (nG <= 8) {
#pragma unroll
      for (int r = 0; r < 4; ++r) {
        int row = nodebase + rbase + r;
        if (row < NN) {
          int slot = batching[row] - g0;
          atomicAdd(&gl[slot * FDIM + cc * 4 + 0], fmaxf(acc[r][0] + b4.x, 0.f));
          atomicAdd(&gl[slot * FDIM + cc * 4 + 1], fmaxf(acc[r][1] + b4.y, 0.f));
          atomicAdd(&gl[slot * FDIM + cc * 4 + 2], fmaxf(acc[r][2] + b4.z, 0.f));
          atomicAdd(&gl[slot * FDIM + cc * 4 + 3], fmaxf(acc[r][3] + b4.w, 0.f));
        }
      }
      __syncthreads();
      for (int i = t; i < nG * FDIM; i += 512) {
        float v = gl[i];
        if (v != 0.f)
          atomicAdd(&gout[(size_t)(g0 + (i >> 7)) * FDIM + (i & 127)], v);
      }
    } else {
#pragma unroll
      for (int r = 0; r < 4; ++r) {
        int row = nodebase + rbase + r;
        if (row < NN) {
          int gid = batching[row];
          atomicAdd(&gout[(size_t)gid * FDIM + cc * 4 + 0], fmaxf(acc[r][0] + b4.x, 0.f));
          atomicAdd(&gout[(size_t)gid * FDIM + cc * 4 + 1], fmaxf(acc[r][1] + b4.y, 0.f));
          atomicAdd(&gout[(size_t)gid * FDIM + cc * 4 + 2], fmaxf(acc[r][2] + b4.z, 0.f));
          atomicAdd(&gout[(size_t)gid * FDIM + cc * 4 + 3], fmaxf(acc[r][3] + b4.w, 0.f));
        }
      }
    }
  }
#undef CVTACC
}

// ---------------- head: FC1 + FC2 + softmax over pooled g ----------------
__global__ __launch_bounds__(128) void head(const float* __restrict__ g,
                                            const float* __restrict__ Wf1,
                                            const float* __restrict__ bf1,
                                            const float* __restrict__ Wf2,
                                            const float* __restrict__ bf2,
                                            float* __restrict__ out) {
  __shared__ float gl[128];
  __shared__ float hl[64];
  __shared__ float ol[10];
  __shared__ float red[2];
  int gid = blockIdx.x, t = threadIdx.x;
  gl[t] = g[(size_t)gid * FDIM + t];
  __syncthreads();
  if (t < NFC1) {
    float h = bf1[t];
    for (int f = 0; f < 128; ++f) h += gl[f] * Wf1[f * NFC1 + t];
    hl[t] = h;
  }
  __syncthreads();
  if (t < NFC2) {
    float o = bf2[t];
    for (int i = 0; i < NFC1; ++i) o += hl[i] * Wf2[i * NFC2 + t];
    ol[t] = o;
  }
  __syncthreads();
  if (t == 0) {
    float m = ol[0];
    for (int i = 1; i < NFC2; ++i) m = fmaxf(m, ol[i]);
    float s = 0.f;
    for (int i = 0; i < NFC2; ++i) s += expf(ol[i] - m);
    red[0] = m;
    red[1] = s;
  }
  __syncthreads();
  if (t < NFC2) out[(size_t)gid * NFC2 + t] = expf(ol[t] - red[0]) / red[1];
}

extern "C" void kernel_launch(void* const* d_in, const int* in_sizes, int n_in,
                              void* d_out, int out_size, void* d_ws, size_t ws_size,
                              hipStream_t stream) {
  const float* node_attr = (const float*)d_in[0];
  const float* Wc = (const float*)d_in[1];   // [3][128][128]
  const float* bc = (const float*)d_in[2];   // [3][128]
  const float* Wf1 = (const float*)d_in[3];  // [128][64]
  const float* bf1 = (const float*)d_in[4];
  const float* Wf2 = (const float*)d_in[5];  // [64][10]
  const float* bf2 = (const float*)d_in[6];
  const int* src = (const int*)d_in[7];
  const int* dst = (const int*)d_in[8];
  const int* batching = (const int*)d_in[9];
  float* out = (float*)d_out;

  char* wsp = (char*)d_ws;
  size_t off = 0;
  auto alloc = [&](size_t bytes) -> void* {
    void* p = wsp + off;
    off += (bytes + 255) & ~(size_t)255;
    return p;
  };
  int* row_off = (int*)alloc((size_t)(NN + 1) * sizeof(int));
  int* gcursor = (int*)alloc(NBUCK * sizeof(int));
  int* esrc = (int*)alloc((size_t)(NE + 8) * sizeof(int));  // +8 pad for quad over-read
  __half* xh0 = (__half*)alloc((size_t)NN * FDIM * sizeof(__half));   // 25.6 MB
  __half* bufA = (__half*)alloc((size_t)NN * FDIM * sizeof(__half));  // 25.6 MB
  __half* bufB = (__half*)alloc((size_t)NN * FDIM * sizeof(__half));  // 25.6 MB
  // staging (16.1 MB) aliases bufB: staging is dead (consumed by build_kernel)
  // before layer-2 writes bufB
  int* staging = (int*)bufB;
  // pooled g (512 KB fp32) aliases bufA: bufA dead after layer-2's gather;
  // memset enqueued after layer-2 launch (stream-ordered)
  float* gbuf = (float*)bufA;

  // CSR build via 2-level counting sort
  hipMemsetAsync(gcursor, 0, NBUCK * sizeof(int), stream);
  bin_kernel<<<(NE + 256 * EPB - 1) / (256 * EPB), 256, 0, stream>>>(src, dst, gcursor, staging);
  build_kernel<<<NBUCK, 256, 0, stream>>>(staging, gcursor, row_off, esrc);

  // node_attr fp32 -> fp16
  cvt_kernel<<<2048, 256, 0, stream>>>((const float4*)node_attr, (uint2*)xh0,
                                       NN * FDIM / 4);

  const int GRID = (NN + 63) / 64;  // 1563

  // layer 1: bufA = fp16(relu(agg(xh0) @ W0 + b0))
  conv_fused<0><<<GRID, 512, 0, stream>>>((const float4*)xh0, row_off, esrc,
                                          Wc, bc, nullptr, bufA, nullptr);
  // layer 2: bufB = fp16(relu(agg(bufA) @ W1 + b1))
  conv_fused<0><<<GRID, 512, 0, stream>>>((const float4*)bufA, row_off, esrc,
                                          Wc + 16384, bc + 128, nullptr, bufB, nullptr);
  // layer 3 fused with global_sum_pool (fp32 epilogue, no x3 write)
  hipMemsetAsync(gbuf, 0, (size_t)NG * FDIM * sizeof(float), stream);
  conv_fused<1><<<GRID, 512, 0, stream>>>((const float4*)bufB, row_off, esrc,
                                          Wc + 32768, bc + 256, batching, nullptr, gbuf);

  // head
  head<<<NG, 128, 0, stream>>>(gbuf, Wf1, bf1, Wf2, bf2, out);
}

// Round 9
// 713.464 us; speedup vs baseline: 1.2107x; 1.2107x over previous
//
#include <hip/hip_runtime.h>
#include <hip/hip_fp16.h>
#include <math.h>

#define NN 100000
#define NE 3200000
#define NG 1024
#define FDIM 128
#define NFC1 64
#define NFC2 10

#define BSHIFT 9
#define NBUCK 196   // ceil(NN/512)
#define CAP 20480   // mean 16384, sigma ~127 -> 32-sigma headroom
#define EPB 16      // edges per thread in bin_kernel

#define NPB 32      // dst nodes per conv block (256 threads = 4 waves)
#define ATS 36      // aT leading-dim stride (32 + 4 pad)

#define RF __builtin_amdgcn_readfirstlane
// quarter-select: quarter q of the wave takes value k_q (static indices only)
#define QSEL(q, v0, v1, v2, v3) ((q) == 0 ? (v0) : (q) == 1 ? (v1) : (q) == 2 ? (v2) : (v3))

// ---------------- pass 1: bin edges into 196 coarse buckets ----------------
// Packed value: (dst & 511) << 17 | src   (src < 2^17, dst_local < 2^9)
__global__ __launch_bounds__(256) void bin_kernel(const int* __restrict__ src,
                                                  const int* __restrict__ dst,
                                                  int* __restrict__ gcursor,
                                                  int* __restrict__ staging) {
  __shared__ int hist[NBUCK];
  __shared__ int base[NBUCK];
  int t = threadIdx.x;
  for (int i = t; i < NBUCK; i += 256) hist[i] = 0;
  __syncthreads();
  size_t e0 = (size_t)blockIdx.x * (256 * EPB);
  int bk[EPB], rank[EPB], val[EPB];
#pragma unroll
  for (int j = 0; j < EPB; ++j) {
    size_t e = e0 + (size_t)j * 256 + t;
    if (e < NE) {
      int d = dst[e];
      int s = src[e];
      bk[j] = d >> BSHIFT;
      val[j] = ((d & 511) << 17) | s;
      rank[j] = atomicAdd(&hist[bk[j]], 1);
    } else {
      bk[j] = -1;
    }
  }
  __syncthreads();
  for (int i = t; i < NBUCK; i += 256) base[i] = atomicAdd(&gcursor[i], hist[i]);
  __syncthreads();
#pragma unroll
  for (int j = 0; j < EPB; ++j) {
    if (bk[j] >= 0) {
      int pos = base[bk[j]] + rank[j];
      if (pos < CAP) staging[(size_t)bk[j] * CAP + pos] = val[j];
    }
  }
}

// ---------------- pass 2: per-bucket CSR finalize (scan fused in) ----------------
__global__ __launch_bounds__(256) void build_kernel(const int* __restrict__ staging,
                                                    const int* __restrict__ gcursor,
                                                    int* __restrict__ row_off,
                                                    int* __restrict__ esrc) {
  __shared__ int ncnt[512];
  __shared__ int noff[513];
  __shared__ int part[256];
  __shared__ int sscan[256];
  int b = blockIdx.x, t = threadIdx.x;
  int gv = (t < NBUCK) ? gcursor[t] : 0;
  sscan[t] = gv;
  __syncthreads();
  for (int st = 1; st < 256; st <<= 1) {
    int u = (t >= st) ? sscan[t - st] : 0;
    __syncthreads();
    sscan[t] += u;
    __syncthreads();
  }
  int cnt = gcursor[b];
  int ebase = sscan[b] - cnt;  // exclusive prefix
  int nbase = b << BSHIFT;
  ncnt[t] = 0;
  ncnt[t + 256] = 0;
  __syncthreads();
  const int* sp = staging + (size_t)b * CAP;
  for (int i = t; i < cnt; i += 256) {
    int dl = sp[i] >> 17;
    atomicAdd(&ncnt[dl], 1);
  }
  __syncthreads();
  int a0 = ncnt[2 * t], a1 = ncnt[2 * t + 1];
  part[t] = a0 + a1;
  __syncthreads();
  for (int st = 1; st < 256; st <<= 1) {
    int u = (t >= st) ? part[t - st] : 0;
    __syncthreads();
    part[t] += u;
    __syncthreads();
  }
  int excl = (t > 0) ? part[t - 1] : 0;
  noff[2 * t] = excl;
  noff[2 * t + 1] = excl + a0;
  if (t == 255) noff[512] = part[255];
  __syncthreads();
  for (int i = t; i <= 512; i += 256) {
    int n = nbase + i;
    if (n <= NN) row_off[n] = ebase + noff[i];
  }
  // reuse ncnt as write cursors
  ncnt[2 * t] = noff[2 * t];
  ncnt[2 * t + 1] = noff[2 * t + 1];
  __syncthreads();
  for (int i = t; i < cnt; i += 256) {
    int v = sp[i];
    int dl = v >> 17;
    int pos = atomicAdd(&ncnt[dl], 1);
    esrc[ebase + pos] = v & 0x1FFFF;
  }
}

// ---------------- fp32 -> fp16 convert (node_attr -> xh0) ----------------
__global__ __launch_bounds__(256) void cvt_kernel(const float4* __restrict__ in,
                                                  uint2* __restrict__ outp, int n) {
  int i = blockIdx.x * 256 + threadIdx.x;
  int stride = gridDim.x * 256;
  for (; i < n; i += stride) {
    float4 v = in[i];
    union { __half2 h; unsigned u; } u0, u1;
    u0.h = __float22half2_rn(make_float2(v.x, v.y));
    u1.h = __float22half2_rn(make_float2(v.z, v.w));
    outp[i] = make_uint2(u0.u, u1.u);
  }
}

// ---------------- fused conv layer: out = relu(gather(xh)@W + bias) -------
// Gather path is fp16 (row = 128 half = 256B); ALL arithmetic fp32.
// CHANGED this round (vs R7): 256 threads = 4 waves, NPB=32 dst nodes/block,
// aT[128][36] (18.4KB) with the pool `gl` buffer UNIONED into aT -> LDS
// 39.4KB -> 18.4KB -> 8 blocks/CU (was 4): raise memory parallelism via TLP
// (R8's ILP attempt cost VGPR and regressed). Per-wave gather structure is
// EXACTLY R7's proven one: quad-edge, 16 lanes x 16B per edge, 16 edges /
// main iter, shfl_xor(16/32) combine, transposed LDS store, fp32 GEMM.
template <int POOL>
__global__ __launch_bounds__(256) void conv_fused(const float4* __restrict__ xh4,
                                                  const int* __restrict__ row_off,
                                                  const int* __restrict__ esrc,
                                                  const float* __restrict__ W,
                                                  const float* __restrict__ bias,
                                                  const int* __restrict__ batching,
                                                  __half* __restrict__ out,
                                                  float* __restrict__ gout) {
  __shared__ __align__(16) float aT[128 * ATS];  // 18432 B; also reused as gl
  __shared__ int sgv[2];
  int t = threadIdx.x;
  int w = t >> 6;      // wave 0..3
  int lane = t & 63;
  int q = lane >> 4;   // edge within quad
  int c = lane & 15;   // 16B chunk within the 256B fp16 row
  int nodebase = blockIdx.x * NPB;

#define CVTACC(fv)                                         \
  {                                                        \
    union { float4 f; __half2 h[4]; } u_;                  \
    u_.f = (fv);                                           \
    float2 p_;                                             \
    p_ = __half22float2(u_.h[0]); a[0] += p_.x; a[1] += p_.y; \
    p_ = __half22float2(u_.h[1]); a[2] += p_.x; a[3] += p_.y; \
    p_ = __half22float2(u_.h[2]); a[4] += p_.x; a[5] += p_.y; \
    p_ = __half22float2(u_.h[3]); a[6] += p_.x; a[7] += p_.y; \
  }

  // ---- phase 1: gather-aggregate 8 nodes for this wave ----
  for (int i = 0; i < 8; ++i) {
    int r = w * 8 + i;                  // 0..31
    int node = nodebase + r;
    int beg = 0, end = 0;
    if (node < NN) {
      beg = RF(row_off[node]);
      end = RF(row_off[node + 1]);
    }
    float a[8] = {0.f, 0.f, 0.f, 0.f, 0.f, 0.f, 0.f, 0.f};
    int e = beg;
    // main: 16 edges / iter (4 quads, 4 x dwordx4 in flight per lane)
    for (; e + 16 <= end; e += 16) {
      int idx[4];
#pragma unroll
      for (int g = 0; g < 4; ++g) {
        int s0 = RF(esrc[e + 4 * g + 0]);
        int s1 = RF(esrc[e + 4 * g + 1]);
        int s2 = RF(esrc[e + 4 * g + 2]);
        int s3 = RF(esrc[e + 4 * g + 3]);
        idx[g] = QSEL(q, s0, s1, s2, s3);
      }
      float4 f[4];
#pragma unroll
      for (int g = 0; g < 4; ++g) f[g] = xh4[(size_t)idx[g] * 16 + c];
#pragma unroll
      for (int g = 0; g < 4; ++g) CVTACC(f[g]);
    }
    // small: 8 edges / iter (2 quads)
    for (; e + 8 <= end; e += 8) {
      int a0 = RF(esrc[e + 0]), a1 = RF(esrc[e + 1]), a2 = RF(esrc[e + 2]), a3 = RF(esrc[e + 3]);
      int b0 = RF(esrc[e + 4]), b1 = RF(esrc[e + 5]), b2 = RF(esrc[e + 6]), b3 = RF(esrc[e + 7]);
      int iA = QSEL(q, a0, a1, a2, a3);
      int iB = QSEL(q, b0, b1, b2, b3);
      float4 fA = xh4[(size_t)iA * 16 + c];
      float4 fB = xh4[(size_t)iB * 16 + c];
      CVTACC(fA)
      CVTACC(fB)
    }
    // final: predicated quad (esrc padded +8 ints, so scalar reads stay in-bounds;
    // lanes with e+q >= end skip the vector load, so garbage indices are never used)
    for (; e < end; e += 4) {
      int a0 = RF(esrc[e + 0]), a1 = RF(esrc[e + 1]), a2 = RF(esrc[e + 2]), a3 = RF(esrc[e + 3]);
      int iA = QSEL(q, a0, a1, a2, a3);
      float4 fA = make_float4(0.f, 0.f, 0.f, 0.f);
      if (e + q < end) fA = xh4[(size_t)iA * 16 + c];
      CVTACC(fA)
    }
    // combine quarters: lanes {c, c+16, c+32, c+48} hold partials of chunk c
#pragma unroll
    for (int j = 0; j < 8; ++j) {
      a[j] += __shfl_xor(a[j], 16);
      a[j] += __shfl_xor(a[j], 32);
    }
    // transposed store: feature f = c*8 + j; this lane writes j = 2q, 2q+1
    float w0 = QSEL(q, a[0], a[2], a[4], a[6]);
    float w1 = QSEL(q, a[1], a[3], a[5], a[7]);
    aT[(c * 8 + 2 * q + 0) * ATS + r] = w0;
    aT[(c * 8 + 2 * q + 1) * ATS + r] = w1;
  }
  __syncthreads();

  // ---- phase 2: GEMM 32x128 tile (fp32) ----
  int rg = lane >> 5;       // 0..1
  int cc = lane & 31;       // cols 4cc..4cc+3
  int rbase = w * 8 + rg * 4;

  float acc[4][4];
#pragma unroll
  for (int r = 0; r < 4; ++r)
#pragma unroll
    for (int j = 0; j < 4; ++j) acc[r][j] = 0.f;

#pragma unroll 4
  for (int k = 0; k < 128; ++k) {
    float4 bv = *(const float4*)(W + k * FDIM + cc * 4);
    float4 a0 = *(const float4*)(&aT[k * ATS + rbase]);
    float ar[4] = {a0.x, a0.y, a0.z, a0.w};
#pragma unroll
    for (int r = 0; r < 4; ++r) {
      acc[r][0] += ar[r] * bv.x;
      acc[r][1] += ar[r] * bv.y;
      acc[r][2] += ar[r] * bv.z;
      acc[r][3] += ar[r] * bv.w;
    }
  }

  float4 b4 = *(const float4*)(bias + cc * 4);

  if (POOL == 0) {
#pragma unroll
    for (int r = 0; r < 4; ++r) {
      int row = nodebase + rbase + r;
      if (row < NN) {
        float ox = fmaxf(acc[r][0] + b4.x, 0.f);
        float oy = fmaxf(acc[r][1] + b4.y, 0.f);
        float oz = fmaxf(acc[r][2] + b4.z, 0.f);
        float ow = fmaxf(acc[r][3] + b4.w, 0.f);
        union { uint2 u2; __half2 h[2]; } pk;
        pk.h[0] = __float22half2_rn(make_float2(ox, oy));
        pk.h[1] = __float22half2_rn(make_float2(oz, ow));
        *(uint2*)(out + (size_t)row * FDIM + cc * 4) = pk.u2;
      }
    }
  } else {
    // fused global_sum_pool (fp32): gl buffer UNIONS into aT -- all waves are
    // done reading aT (acc is in registers), but must barrier before overwrite.
    float* gl = aT;
    __syncthreads();
    if (t == 0) {
      sgv[0] = batching[nodebase];
      int last = nodebase + NPB - 1;
      if (last >= NN) last = NN - 1;
      sgv[1] = batching[last] - sgv[0] + 1;
    }
    for (int i = t; i < 8 * FDIM; i += 256) gl[i] = 0.f;
    __syncthreads();
    int g0 = sgv[0], nG = sgv[1];
    if (nG <= 8) {
#pragma unroll
      for (int r = 0; r < 4; ++r) {
        int row = nodebase + rbase + r;
        if (row < NN) {
          int slot = batching[row] - g0;
          atomicAdd(&gl[slot * FDIM + cc * 4 + 0], fmaxf(acc[r][0] + b4.x, 0.f));
          atomicAdd(&gl[slot * FDIM + cc * 4 + 1], fmaxf(acc[r][1] + b4.y, 0.f));
          atomicAdd(&gl[slot * FDIM + cc * 4 + 2], fmaxf(acc[r][2] + b4.z, 0.f));
          atomicAdd(&gl[slot * FDIM + cc * 4 + 3], fmaxf(acc[r][3] + b4.w, 0.f));
        }
      }
      __syncthreads();
      for (int i = t; i < nG * FDIM; i += 256) {
        float v = gl[i];
        if (v != 0.f)
          atomicAdd(&gout[(size_t)(g0 + (i >> 7)) * FDIM + (i & 127)], v);
      }
    } else {
#pragma unroll
      for (int r = 0; r < 4; ++r) {
        int row = nodebase + rbase + r;
        if (row < NN) {
          int gid = batching[row];
          atomicAdd(&gout[(size_t)gid * FDIM + cc * 4 + 0], fmaxf(acc[r][0] + b4.x, 0.f));
          atomicAdd(&gout[(size_t)gid * FDIM + cc * 4 + 1], fmaxf(acc[r][1] + b4.y, 0.f));
          atomicAdd(&gout[(size_t)gid * FDIM + cc * 4 + 2], fmaxf(acc[r][2] + b4.z, 0.f));
          atomicAdd(&gout[(size_t)gid * FDIM + cc * 4 + 3], fmaxf(acc[r][3] + b4.w, 0.f));
        }
      }
    }
  }
#undef CVTACC
}

// ---------------- head: FC1 + FC2 + softmax over pooled g ----------------
__global__ __launch_bounds__(128) void head(const float* __restrict__ g,
                                            const float* __restrict__ Wf1,
                                            const float* __restrict__ bf1,
                                            const float* __restrict__ Wf2,
                                            const float* __restrict__ bf2,
                                            float* __restrict__ out) {
  __shared__ float gl[128];
  __shared__ float hl[64];
  __shared__ float ol[10];
  __shared__ float red[2];
  int gid = blockIdx.x, t = threadIdx.x;
  gl[t] = g[(size_t)gid * FDIM + t];
  __syncthreads();
  if (t < NFC1) {
    float h = bf1[t];
    for (int f = 0; f < 128; ++f) h += gl[f] * Wf1[f * NFC1 + t];
    hl[t] = h;
  }
  __syncthreads();
  if (t < NFC2) {
    float o = bf2[t];
    for (int i = 0; i < NFC1; ++i) o += hl[i] * Wf2[i * NFC2 + t];
    ol[t] = o;
  }
  __syncthreads();
  if (t == 0) {
    float m = ol[0];
    for (int i = 1; i < NFC2; ++i) m = fmaxf(m, ol[i]);
    float s = 0.f;
    for (int i = 0; i < NFC2; ++i) s += expf(ol[i] - m);
    red[0] = m;
    red[1] = s;
  }
  __syncthreads();
  if (t < NFC2) out[(size_t)gid * NFC2 + t] = expf(ol[t] - red[0]) / red[1];
}

extern "C" void kernel_launch(void* const* d_in, const int* in_sizes, int n_in,
                              void* d_out, int out_size, void* d_ws, size_t ws_size,
                              hipStream_t stream) {
  const float* node_attr = (const float*)d_in[0];
  const float* Wc = (const float*)d_in[1];   // [3][128][128]
  const float* bc = (const float*)d_in[2];   // [3][128]
  const float* Wf1 = (const float*)d_in[3];  // [128][64]
  const float* bf1 = (const float*)d_in[4];
  const float* Wf2 = (const float*)d_in[5];  // [64][10]
  const float* bf2 = (const float*)d_in[6];
  const int* src = (const int*)d_in[7];
  const int* dst = (const int*)d_in[8];
  const int* batching = (const int*)d_in[9];
  float* out = (float*)d_out;

  char* wsp = (char*)d_ws;
  size_t off = 0;
  auto alloc = [&](size_t bytes) -> void* {
    void* p = wsp + off;
    off += (bytes + 255) & ~(size_t)255;
    return p;
  };
  int* row_off = (int*)alloc((size_t)(NN + 1) * sizeof(int));
  int* gcursor = (int*)alloc(NBUCK * sizeof(int));
  int* esrc = (int*)alloc((size_t)(NE + 8) * sizeof(int));  // +8 pad for quad over-read
  __half* xh0 = (__half*)alloc((size_t)NN * FDIM * sizeof(__half));   // 25.6 MB
  __half* bufA = (__half*)alloc((size_t)NN * FDIM * sizeof(__half));  // 25.6 MB
  __half* bufB = (__half*)alloc((size_t)NN * FDIM * sizeof(__half));  // 25.6 MB
  // staging (16.1 MB) aliases bufB: staging is dead (consumed by build_kernel)
  // before layer-2 writes bufB
  int* staging = (int*)bufB;
  // pooled g (512 KB fp32) aliases bufA: bufA dead after layer-2's gather;
  // memset enqueued after layer-2 launch (stream-ordered)
  float* gbuf = (float*)bufA;

  // CSR build via 2-level counting sort
  hipMemsetAsync(gcursor, 0, NBUCK * sizeof(int), stream);
  bin_kernel<<<(NE + 256 * EPB - 1) / (256 * EPB), 256, 0, stream>>>(src, dst, gcursor, staging);
  build_kernel<<<NBUCK, 256, 0, stream>>>(staging, gcursor, row_off, esrc);

  // node_attr fp32 -> fp16
  cvt_kernel<<<2048, 256, 0, stream>>>((const float4*)node_attr, (uint2*)xh0,
                                       NN * FDIM / 4);

  const int GRID = (NN + NPB - 1) / NPB;  // 3125

  // layer 1: bufA = fp16(relu(agg(xh0) @ W0 + b0))
  conv_fused<0><<<GRID, 256, 0, stream>>>((const float4*)xh0, row_off, esrc,
                                          Wc, bc, nullptr, bufA, nullptr);
  // layer 2: bufB = fp16(relu(agg(bufA) @ W1 + b1))
  conv_fused<0><<<GRID, 256, 0, stream>>>((const float4*)bufA, row_off, esrc,
                                          Wc + 16384, bc + 128, nullptr, bufB, nullptr);
  // layer 3 fused with global_sum_pool (fp32 epilogue, no x3 write)
  hipMemsetAsync(gbuf, 0, (size_t)NG * FDIM * sizeof(float), stream);
  conv_fused<1><<<GRID, 256, 0, stream>>>((const float4*)bufB, row_off, esrc,
                                          Wc + 32768, bc + 256, batching, nullptr, gbuf);

  // head
  head<<<NG, 128, 0, stream>>>(gbuf, Wf1, bf1, Wf2, bf2, out);
}

// Round 10
// 684.787 us; speedup vs baseline: 1.2614x; 1.0419x over previous
//
#include <hip/hip_runtime.h>
#include <hip/hip_fp16.h>
#include <math.h>

#define NN 100000
#define NE 3200000
#define NG 1024
#define FDIM 128
#define NFC1 64
#define NFC2 10

#define BSHIFT 9
#define NBUCK 196   // ceil(NN/512)
#define CAP 20480   // mean 16384, sigma ~127 -> 32-sigma headroom
#define EPB 16      // edges per thread in bin_kernel

#define NPB 32      // dst nodes per conv block (256 threads = 4 waves)
#define ATS 36      // aT leading-dim stride (32 + 4 pad)

#define RF __builtin_amdgcn_readfirstlane
// quarter-select: quarter q of the wave takes value k_q (static indices only)
#define QSEL(q, v0, v1, v2, v3) ((q) == 0 ? (v0) : (q) == 1 ? (v1) : (q) == 2 ? (v2) : (v3))

// ---------------- pass 1: bin edges into 196 coarse buckets ----------------
// Packed value: (dst & 511) << 17 | src   (src < 2^17, dst_local < 2^9)
__global__ __launch_bounds__(256) void bin_kernel(const int* __restrict__ src,
                                                  const int* __restrict__ dst,
                                                  int* __restrict__ gcursor,
                                                  int* __restrict__ staging) {
  __shared__ int hist[NBUCK];
  __shared__ int base[NBUCK];
  int t = threadIdx.x;
  for (int i = t; i < NBUCK; i += 256) hist[i] = 0;
  __syncthreads();
  size_t e0 = (size_t)blockIdx.x * (256 * EPB);
  int bk[EPB], rank[EPB], val[EPB];
#pragma unroll
  for (int j = 0; j < EPB; ++j) {
    size_t e = e0 + (size_t)j * 256 + t;
    if (e < NE) {
      int d = dst[e];
      int s = src[e];
      bk[j] = d >> BSHIFT;
      val[j] = ((d & 511) << 17) | s;
      rank[j] = atomicAdd(&hist[bk[j]], 1);
    } else {
      bk[j] = -1;
    }
  }
  __syncthreads();
  for (int i = t; i < NBUCK; i += 256) base[i] = atomicAdd(&gcursor[i], hist[i]);
  __syncthreads();
#pragma unroll
  for (int j = 0; j < EPB; ++j) {
    if (bk[j] >= 0) {
      int pos = base[bk[j]] + rank[j];
      if (pos < CAP) staging[(size_t)bk[j] * CAP + pos] = val[j];
    }
  }
}

// ---------------- pass 2: per-bucket CSR finalize (scan fused in) ----------------
__global__ __launch_bounds__(256) void build_kernel(const int* __restrict__ staging,
                                                    const int* __restrict__ gcursor,
                                                    int* __restrict__ row_off,
                                                    int* __restrict__ esrc) {
  __shared__ int ncnt[512];
  __shared__ int noff[513];
  __shared__ int part[256];
  __shared__ int sscan[256];
  int b = blockIdx.x, t = threadIdx.x;
  int gv = (t < NBUCK) ? gcursor[t] : 0;
  sscan[t] = gv;
  __syncthreads();
  for (int st = 1; st < 256; st <<= 1) {
    int u = (t >= st) ? sscan[t - st] : 0;
    __syncthreads();
    sscan[t] += u;
    __syncthreads();
  }
  int cnt = gcursor[b];
  int ebase = sscan[b] - cnt;  // exclusive prefix
  int nbase = b << BSHIFT;
  ncnt[t] = 0;
  ncnt[t + 256] = 0;
  __syncthreads();
  const int* sp = staging + (size_t)b * CAP;
  for (int i = t; i < cnt; i += 256) {
    int dl = sp[i] >> 17;
    atomicAdd(&ncnt[dl], 1);
  }
  __syncthreads();
  int a0 = ncnt[2 * t], a1 = ncnt[2 * t + 1];
  part[t] = a0 + a1;
  __syncthreads();
  for (int st = 1; st < 256; st <<= 1) {
    int u = (t >= st) ? part[t - st] : 0;
    __syncthreads();
    part[t] += u;
    __syncthreads();
  }
  int excl = (t > 0) ? part[t - 1] : 0;
  noff[2 * t] = excl;
  noff[2 * t + 1] = excl + a0;
  if (t == 255) noff[512] = part[255];
  __syncthreads();
  for (int i = t; i <= 512; i += 256) {
    int n = nbase + i;
    if (n <= NN) row_off[n] = ebase + noff[i];
  }
  // reuse ncnt as write cursors
  ncnt[2 * t] = noff[2 * t];
  ncnt[2 * t + 1] = noff[2 * t + 1];
  __syncthreads();
  for (int i = t; i < cnt; i += 256) {
    int v = sp[i];
    int dl = v >> 17;
    int pos = atomicAdd(&ncnt[dl], 1);
    esrc[ebase + pos] = v & 0x1FFFF;
  }
}

// ---------------- fp32 -> fp16 convert (node_attr -> xh0) ----------------
__global__ __launch_bounds__(256) void cvt_kernel(const float4* __restrict__ in,
                                                  uint2* __restrict__ outp, int n) {
  int i = blockIdx.x * 256 + threadIdx.x;
  int stride = gridDim.x * 256;
  for (; i < n; i += stride) {
    float4 v = in[i];
    union { __half2 h; unsigned u; } u0, u1;
    u0.h = __float22half2_rn(make_float2(v.x, v.y));
    u1.h = __float22half2_rn(make_float2(v.z, v.w));
    outp[i] = make_uint2(u0.u, u1.u);
  }
}

// ---------------- fused conv layer: out = relu(gather(xh)@W + bias) -------
// Gather path fp16 (row = 256B); GEMM/epilogue fp32.
// CHANGED this round (single theory: per-edge SIMD issue cost is the binder):
//  1. idx loads are per-lane VECTOR loads esrc[e + 4g + q] (one coalesced
//     16B segment per quad) -- replaces 16 scalar loads + 12 v_cndmask/iter.
//  2. accumulate in PACKED fp16 (v_pk_add_f16 via __hadd2): 4 VALU per 16B
//     instead of 12 (cvt+add). Convert to fp32 once per row after the loop;
//     shfl combine + GEMM + epilogue stay fp32.
// Structure (quad-edge, 4 loads in flight, 256 thr / 32 nodes, aT[128][36],
// gl unioned into aT) is R9's measured-best, unchanged.
template <int POOL>
__global__ __launch_bounds__(256) void conv_fused(const float4* __restrict__ xh4,
                                                  const int* __restrict__ row_off,
                                                  const int* __restrict__ esrc,
                                                  const float* __restrict__ W,
                                                  const float* __restrict__ bias,
                                                  const int* __restrict__ batching,
                                                  __half* __restrict__ out,
                                                  float* __restrict__ gout) {
  __shared__ __align__(16) float aT[128 * ATS];  // 18432 B; also reused as gl
  __shared__ int sgv[2];
  int t = threadIdx.x;
  int w = t >> 6;      // wave 0..3
  int lane = t & 63;
  int q = lane >> 4;   // edge within quad
  int c = lane & 15;   // 16B chunk within the 256B fp16 row
  int nodebase = blockIdx.x * NPB;

#define PKACC(fv)                                          \
  {                                                        \
    union { float4 f; __half2 h[4]; } u_;                  \
    u_.f = (fv);                                           \
    a[0] = __hadd2(a[0], u_.h[0]);                         \
    a[1] = __hadd2(a[1], u_.h[1]);                         \
    a[2] = __hadd2(a[2], u_.h[2]);                         \
    a[3] = __hadd2(a[3], u_.h[3]);                         \
  }

  // ---- phase 1: gather-aggregate 8 nodes for this wave ----
  for (int i = 0; i < 8; ++i) {
    int r = w * 8 + i;                  // 0..31
    int node = nodebase + r;
    int beg = 0, end = 0;
    if (node < NN) {
      beg = RF(row_off[node]);
      end = RF(row_off[node + 1]);
    }
    __half2 z = __float2half2_rn(0.f);
    __half2 a[4] = {z, z, z, z};
    int e = beg;
    // main: 16 edges / iter (4 quads; idx = per-lane vector load; 4 dwordx4
    // data loads in flight)
    for (; e + 16 <= end; e += 16) {
      int i0 = esrc[e + 0 + q];
      int i1 = esrc[e + 4 + q];
      int i2 = esrc[e + 8 + q];
      int i3 = esrc[e + 12 + q];
      float4 f0 = xh4[(size_t)i0 * 16 + c];
      float4 f1 = xh4[(size_t)i1 * 16 + c];
      float4 f2 = xh4[(size_t)i2 * 16 + c];
      float4 f3 = xh4[(size_t)i3 * 16 + c];
      PKACC(f0)
      PKACC(f1)
      PKACC(f2)
      PKACC(f3)
    }
    // small: 8 edges / iter (2 quads)
    for (; e + 8 <= end; e += 8) {
      int i0 = esrc[e + 0 + q];
      int i1 = esrc[e + 4 + q];
      float4 f0 = xh4[(size_t)i0 * 16 + c];
      float4 f1 = xh4[(size_t)i1 * 16 + c];
      PKACC(f0)
      PKACC(f1)
    }
    // final: predicated quad (esrc padded +8 ints -> idx read safe; data load
    // exec-masked for lanes with e+q >= end, so garbage idx is never used)
    for (; e < end; e += 4) {
      int i0 = esrc[e + q];
      if (e + q < end) {
        float4 f0 = xh4[(size_t)i0 * 16 + c];
        PKACC(f0)
      }
    }
    // widen to fp32 once per row
    float af[8];
    {
      float2 p0 = __half22float2(a[0]);
      float2 p1 = __half22float2(a[1]);
      float2 p2 = __half22float2(a[2]);
      float2 p3 = __half22float2(a[3]);
      af[0] = p0.x; af[1] = p0.y;
      af[2] = p1.x; af[3] = p1.y;
      af[4] = p2.x; af[5] = p2.y;
      af[6] = p3.x; af[7] = p3.y;
    }
    // combine quarters: lanes {c, c+16, c+32, c+48} hold partials of chunk c
#pragma unroll
    for (int j = 0; j < 8; ++j) {
      af[j] += __shfl_xor(af[j], 16);
      af[j] += __shfl_xor(af[j], 32);
    }
    // transposed store: feature f = c*8 + j; this lane writes j = 2q, 2q+1
    float w0 = QSEL(q, af[0], af[2], af[4], af[6]);
    float w1 = QSEL(q, af[1], af[3], af[5], af[7]);
    aT[(c * 8 + 2 * q + 0) * ATS + r] = w0;
    aT[(c * 8 + 2 * q + 1) * ATS + r] = w1;
  }
  __syncthreads();

  // ---- phase 2: GEMM 32x128 tile (fp32) ----
  int rg = lane >> 5;       // 0..1
  int cc = lane & 31;       // cols 4cc..4cc+3
  int rbase = w * 8 + rg * 4;

  float acc[4][4];
#pragma unroll
  for (int r = 0; r < 4; ++r)
#pragma unroll
    for (int j = 0; j < 4; ++j) acc[r][j] = 0.f;

#pragma unroll 4
  for (int k = 0; k < 128; ++k) {
    float4 bv = *(const float4*)(W + k * FDIM + cc * 4);
    float4 a0 = *(const float4*)(&aT[k * ATS + rbase]);
    float ar[4] = {a0.x, a0.y, a0.z, a0.w};
#pragma unroll
    for (int r = 0; r < 4; ++r) {
      acc[r][0] += ar[r] * bv.x;
      acc[r][1] += ar[r] * bv.y;
      acc[r][2] += ar[r] * bv.z;
      acc[r][3] += ar[r] * bv.w;
    }
  }

  float4 b4 = *(const float4*)(bias + cc * 4);

  if (POOL == 0) {
#pragma unroll
    for (int r = 0; r < 4; ++r) {
      int row = nodebase + rbase + r;
      if (row < NN) {
        float ox = fmaxf(acc[r][0] + b4.x, 0.f);
        float oy = fmaxf(acc[r][1] + b4.y, 0.f);
        float oz = fmaxf(acc[r][2] + b4.z, 0.f);
        float ow = fmaxf(acc[r][3] + b4.w, 0.f);
        union { uint2 u2; __half2 h[2]; } pk;
        pk.h[0] = __float22half2_rn(make_float2(ox, oy));
        pk.h[1] = __float22half2_rn(make_float2(oz, ow));
        *(uint2*)(out + (size_t)row * FDIM + cc * 4) = pk.u2;
      }
    }
  } else {
    // fused global_sum_pool (fp32): gl buffer UNIONS into aT -- all waves are
    // done reading aT (acc is in registers), but must barrier before overwrite.
    float* gl = aT;
    __syncthreads();
    if (t == 0) {
      sgv[0] = batching[nodebase];
      int last = nodebase + NPB - 1;
      if (last >= NN) last = NN - 1;
      sgv[1] = batching[last] - sgv[0] + 1;
    }
    for (int i = t; i < 8 * FDIM; i += 256) gl[i] = 0.f;
    __syncthreads();
    int g0 = sgv[0], nG = sgv[1];
    if (nG <= 8) {
#pragma unroll
      for (int r = 0; r < 4; ++r) {
        int row = nodebase + rbase + r;
        if (row < NN) {
          int slot = batching[row] - g0;
          atomicAdd(&gl[slot * FDIM + cc * 4 + 0], fmaxf(acc[r][0] + b4.x, 0.f));
          atomicAdd(&gl[slot * FDIM + cc * 4 + 1], fmaxf(acc[r][1] + b4.y, 0.f));
          atomicAdd(&gl[slot * FDIM + cc * 4 + 2], fmaxf(acc[r][2] + b4.z, 0.f));
          atomicAdd(&gl[slot * FDIM + cc * 4 + 3], fmaxf(acc[r][3] + b4.w, 0.f));
        }
      }
      __syncthreads();
      for (int i = t; i < nG * FDIM; i += 256) {
        float v = gl[i];
        if (v != 0.f)
          atomicAdd(&gout[(size_t)(g0 + (i >> 7)) * FDIM + (i & 127)], v);
      }
    } else {
#pragma unroll
      for (int r = 0; r < 4; ++r) {
        int row = nodebase + rbase + r;
        if (row < NN) {
          int gid = batching[row];
          atomicAdd(&gout[(size_t)gid * FDIM + cc * 4 + 0], fmaxf(acc[r][0] + b4.x, 0.f));
          atomicAdd(&gout[(size_t)gid * FDIM + cc * 4 + 1], fmaxf(acc[r][1] + b4.y, 0.f));
          atomicAdd(&gout[(size_t)gid * FDIM + cc * 4 + 2], fmaxf(acc[r][2] + b4.z, 0.f));
          atomicAdd(&gout[(size_t)gid * FDIM + cc * 4 + 3], fmaxf(acc[r][3] + b4.w, 0.f));
        }
      }
    }
  }
#undef PKACC
}

// ---------------- head: FC1 + FC2 + softmax over pooled g ----------------
__global__ __launch_bounds__(128) void head(const float* __restrict__ g,
                                            const float* __restrict__ Wf1,
                                            const float* __restrict__ bf1,
                                            const float* __restrict__ Wf2,
                                            const float* __restrict__ bf2,
                                            float* __restrict__ out) {
  __shared__ float gl[128];
  __shared__ float hl[64];
  __shared__ float ol[10];
  __shared__ float red[2];
  int gid = blockIdx.x, t = threadIdx.x;
  gl[t] = g[(size_t)gid * FDIM + t];
  __syncthreads();
  if (t < NFC1) {
    float h = bf1[t];
    for (int f = 0; f < 128; ++f) h += gl[f] * Wf1[f * NFC1 + t];
    hl[t] = h;
  }
  __syncthreads();
  if (t < NFC2) {
    float o = bf2[t];
    for (int i = 0; i < NFC1; ++i) o += hl[i] * Wf2[i * NFC2 + t];
    ol[t] = o;
  }
  __syncthreads();
  if (t == 0) {
    float m = ol[0];
    for (int i = 1; i < NFC2; ++i) m = fmaxf(m, ol[i]);
    float s = 0.f;
    for (int i = 0; i < NFC2; ++i) s += expf(ol[i] - m);
    red[0] = m;
    red[1] = s;
  }
  __syncthreads();
  if (t < NFC2) out[(size_t)gid * NFC2 + t] = expf(ol[t] - red[0]) / red[1];
}

extern "C" void kernel_launch(void* const* d_in, const int* in_sizes, int n_in,
                              void* d_out, int out_size, void* d_ws, size_t ws_size,
                              hipStream_t stream) {
  const float* node_attr = (const float*)d_in[0];
  const float* Wc = (const float*)d_in[1];   // [3][128][128]
  const float* bc = (const float*)d_in[2];   // [3][128]
  const float* Wf1 = (const float*)d_in[3];  // [128][64]
  const float* bf1 = (const float*)d_in[4];
  const float* Wf2 = (const float*)d_in[5];  // [64][10]
  const float* bf2 = (const float*)d_in[6];
  const int* src = (const int*)d_in[7];
  const int* dst = (const int*)d_in[8];
  const int* batching = (const int*)d_in[9];
  float* out = (float*)d_out;

  char* wsp = (char*)d_ws;
  size_t off = 0;
  auto alloc = [&](size_t bytes) -> void* {
    void* p = wsp + off;
    off += (bytes + 255) & ~(size_t)255;
    return p;
  };
  int* row_off = (int*)alloc((size_t)(NN + 1) * sizeof(int));
  int* gcursor = (int*)alloc(NBUCK * sizeof(int));
  int* esrc = (int*)alloc((size_t)(NE + 8) * sizeof(int));  // +8 pad for quad over-read
  __half* xh0 = (__half*)alloc((size_t)NN * FDIM * sizeof(__half));   // 25.6 MB
  __half* bufA = (__half*)alloc((size_t)NN * FDIM * sizeof(__half));  // 25.6 MB
  __half* bufB = (__half*)alloc((size_t)NN * FDIM * sizeof(__half));  // 25.6 MB
  // staging (16.1 MB) aliases bufB: staging is dead (consumed by build_kernel)
  // before layer-2 writes bufB
  int* staging = (int*)bufB;
  // pooled g (512 KB fp32) aliases bufA: bufA dead after layer-2's gather;
  // memset enqueued after layer-2 launch (stream-ordered)
  float* gbuf = (float*)bufA;

  // CSR build via 2-level counting sort
  hipMemsetAsync(gcursor, 0, NBUCK * sizeof(int), stream);
  bin_kernel<<<(NE + 256 * EPB - 1) / (256 * EPB), 256, 0, stream>>>(src, dst, gcursor, staging);
  build_kernel<<<NBUCK, 256, 0, stream>>>(staging, gcursor, row_off, esrc);

  // node_attr fp32 -> fp16
  cvt_kernel<<<2048, 256, 0, stream>>>((const float4*)node_attr, (uint2*)xh0,
                                       NN * FDIM / 4);

  const int GRID = (NN + NPB - 1) / NPB;  // 3125

  // layer 1: bufA = fp16(relu(agg(xh0) @ W0 + b0))
  conv_fused<0><<<GRID, 256, 0, stream>>>((const float4*)xh0, row_off, esrc,
                                          Wc, bc, nullptr, bufA, nullptr);
  // layer 2: bufB = fp16(relu(agg(bufA) @ W1 + b1))
  conv_fused<0><<<GRID, 256, 0, stream>>>((const float4*)bufA, row_off, esrc,
                                          Wc + 16384, bc + 128, nullptr, bufB, nullptr);
  // layer 3 fused with global_sum_pool (fp32 epilogue, no x3 write)
  hipMemsetAsync(gbuf, 0, (size_t)NG * FDIM * sizeof(float), stream);
  conv_fused<1><<<GRID, 256, 0, stream>>>((const float4*)bufB, row_off, esrc,
                                          Wc + 32768, bc + 256, batching, nullptr, gbuf);

  // head
  head<<<NG, 128, 0, stream>>>(gbuf, Wf1, bf1, Wf2, bf2, out);
}

// Round 11
// 682.988 us; speedup vs baseline: 1.2648x; 1.0026x over previous
//
#include <hip/hip_runtime.h>
#include <hip/hip_fp16.h>
#include <math.h>

#define NN 100000
#define NE 3200000
#define NG 1024
#define FDIM 128
#define NFC1 64
#define NFC2 10

#define BSHIFT 9
#define NBUCK 196   // ceil(NN/512)
#define CAP 20480   // mean 16384, sigma ~127 -> 32-sigma headroom
#define EPB 16      // edges per thread in bin_kernel

#define NPB 32      // dst nodes per conv block (256 threads = 4 waves)
#define ATS 36      // aT leading-dim stride (32 + 4 pad)

#define RF __builtin_amdgcn_readfirstlane
// quarter-select: quarter q of the wave takes value k_q (static indices only)
#define QSEL(q, v0, v1, v2, v3) ((q) == 0 ? (v0) : (q) == 1 ? (v1) : (q) == 2 ? (v2) : (v3))

// ---------------- pass 1: bin edges into 196 coarse buckets ----------------
// Packed value: (dst & 511) << 17 | src   (src < 2^17, dst_local < 2^9)
__global__ __launch_bounds__(256) void bin_kernel(const int* __restrict__ src,
                                                  const int* __restrict__ dst,
                                                  int* __restrict__ gcursor,
                                                  int* __restrict__ staging) {
  __shared__ int hist[NBUCK];
  __shared__ int base[NBUCK];
  int t = threadIdx.x;
  for (int i = t; i < NBUCK; i += 256) hist[i] = 0;
  __syncthreads();
  size_t e0 = (size_t)blockIdx.x * (256 * EPB);
  int bk[EPB], rank[EPB], val[EPB];
#pragma unroll
  for (int j = 0; j < EPB; ++j) {
    size_t e = e0 + (size_t)j * 256 + t;
    if (e < NE) {
      int d = dst[e];
      int s = src[e];
      bk[j] = d >> BSHIFT;
      val[j] = ((d & 511) << 17) | s;
      rank[j] = atomicAdd(&hist[bk[j]], 1);
    } else {
      bk[j] = -1;
    }
  }
  __syncthreads();
  for (int i = t; i < NBUCK; i += 256) base[i] = atomicAdd(&gcursor[i], hist[i]);
  __syncthreads();
#pragma unroll
  for (int j = 0; j < EPB; ++j) {
    if (bk[j] >= 0) {
      int pos = base[bk[j]] + rank[j];
      if (pos < CAP) staging[(size_t)bk[j] * CAP + pos] = val[j];
    }
  }
}

// ---------------- pass 2: per-bucket CSR finalize (scan fused in) ----------------
__global__ __launch_bounds__(256) void build_kernel(const int* __restrict__ staging,
                                                    const int* __restrict__ gcursor,
                                                    int* __restrict__ row_off,
                                                    int* __restrict__ esrc) {
  __shared__ int ncnt[512];
  __shared__ int noff[513];
  __shared__ int part[256];
  __shared__ int sscan[256];
  int b = blockIdx.x, t = threadIdx.x;
  int gv = (t < NBUCK) ? gcursor[t] : 0;
  sscan[t] = gv;
  __syncthreads();
  for (int st = 1; st < 256; st <<= 1) {
    int u = (t >= st) ? sscan[t - st] : 0;
    __syncthreads();
    sscan[t] += u;
    __syncthreads();
  }
  int cnt = gcursor[b];
  int ebase = sscan[b] - cnt;  // exclusive prefix
  int nbase = b << BSHIFT;
  ncnt[t] = 0;
  ncnt[t + 256] = 0;
  __syncthreads();
  const int* sp = staging + (size_t)b * CAP;
  for (int i = t; i < cnt; i += 256) {
    int dl = sp[i] >> 17;
    atomicAdd(&ncnt[dl], 1);
  }
  __syncthreads();
  int a0 = ncnt[2 * t], a1 = ncnt[2 * t + 1];
  part[t] = a0 + a1;
  __syncthreads();
  for (int st = 1; st < 256; st <<= 1) {
    int u = (t >= st) ? part[t - st] : 0;
    __syncthreads();
    part[t] += u;
    __syncthreads();
  }
  int excl = (t > 0) ? part[t - 1] : 0;
  noff[2 * t] = excl;
  noff[2 * t + 1] = excl + a0;
  if (t == 255) noff[512] = part[255];
  __syncthreads();
  for (int i = t; i <= 512; i += 256) {
    int n = nbase + i;
    if (n <= NN) row_off[n] = ebase + noff[i];
  }
  // reuse ncnt as write cursors
  ncnt[2 * t] = noff[2 * t];
  ncnt[2 * t + 1] = noff[2 * t + 1];
  __syncthreads();
  for (int i = t; i < cnt; i += 256) {
    int v = sp[i];
    int dl = v >> 17;
    int pos = atomicAdd(&ncnt[dl], 1);
    esrc[ebase + pos] = v & 0x1FFFF;
  }
}

// ---------------- fp32 -> fp16 convert (node_attr -> xh0) ----------------
__global__ __launch_bounds__(256) void cvt_kernel(const float4* __restrict__ in,
                                                  uint2* __restrict__ outp, int n) {
  int i = blockIdx.x * 256 + threadIdx.x;
  int stride = gridDim.x * 256;
  for (; i < n; i += stride) {
    float4 v = in[i];
    union { __half2 h; unsigned u; } u0, u1;
    u0.h = __float22half2_rn(make_float2(v.x, v.y));
    u1.h = __float22half2_rn(make_float2(v.z, v.w));
    outp[i] = make_uint2(u0.u, u1.u);
  }
}

// ---------------- fused conv layer: out = relu(gather(xh)@W + bias) -------
// Gather path fp16 (row = 256B); GEMM/epilogue fp32.
// CHANGED this round (theory: per-wave cache-LINE MLP is the binder; R1's
// fp32 kernel sustained 43 G lines/s with 8 dwordx4 in flight vs R10's 26
// G lines/s with 4): main loop widened to 32 edges / iter = 8 quads =
// 8 idx dword loads + 8 dwordx4 data loads = 128 B/lane in flight, on
// R10's cheap vector-idx base (R8's failed 8-deep used 32 readfirstlane +
// 24 cndmask per iter -- that overhead is gone). Dual accumulator sets
// break the packed-add dependency chain. __launch_bounds__(256,6) caps
// regalloc (~85 VGPR) to prevent spill/occupancy surprises.
// Everything else identical to R10 (measured best: 208.5 us/layer).
template <int POOL>
__global__ __launch_bounds__(256, 6) void conv_fused(const float4* __restrict__ xh4,
                                                     const int* __restrict__ row_off,
                                                     const int* __restrict__ esrc,
                                                     const float* __restrict__ W,
                                                     const float* __restrict__ bias,
                                                     const int* __restrict__ batching,
                                                     __half* __restrict__ out,
                                                     float* __restrict__ gout) {
  __shared__ __align__(16) float aT[128 * ATS];  // 18432 B; also reused as gl
  __shared__ int sgv[2];
  int t = threadIdx.x;
  int w = t >> 6;      // wave 0..3
  int lane = t & 63;
  int q = lane >> 4;   // edge within quad
  int c = lane & 15;   // 16B chunk within the 256B fp16 row
  int nodebase = blockIdx.x * NPB;

#define PKACC(A, fv)                                       \
  {                                                        \
    union { float4 f; __half2 h[4]; } u_;                  \
    u_.f = (fv);                                           \
    A[0] = __hadd2(A[0], u_.h[0]);                         \
    A[1] = __hadd2(A[1], u_.h[1]);                         \
    A[2] = __hadd2(A[2], u_.h[2]);                         \
    A[3] = __hadd2(A[3], u_.h[3]);                         \
  }

  // ---- phase 1: gather-aggregate 8 nodes for this wave ----
  for (int i = 0; i < 8; ++i) {
    int r = w * 8 + i;                  // 0..31
    int node = nodebase + r;
    int beg = 0, end = 0;
    if (node < NN) {
      beg = RF(row_off[node]);
      end = RF(row_off[node + 1]);
    }
    __half2 z = __float2half2_rn(0.f);
    __half2 a[4] = {z, z, z, z};
    __half2 b[4] = {z, z, z, z};
    int e = beg;
    // main: 32 edges / iter (8 quads; 8 dwordx4 = 128B/lane in flight)
    for (; e + 32 <= end; e += 32) {
      int ix[8];
#pragma unroll
      for (int g = 0; g < 8; ++g) ix[g] = esrc[e + 4 * g + q];
      float4 f[8];
#pragma unroll
      for (int g = 0; g < 8; ++g) f[g] = xh4[(size_t)ix[g] * 16 + c];
#pragma unroll
      for (int g = 0; g < 8; g += 2) {
        PKACC(a, f[g])
        PKACC(b, f[g + 1])
      }
    }
    // mid: 16 edges / iter (4 quads)
    for (; e + 16 <= end; e += 16) {
      int i0 = esrc[e + 0 + q];
      int i1 = esrc[e + 4 + q];
      int i2 = esrc[e + 8 + q];
      int i3 = esrc[e + 12 + q];
      float4 f0 = xh4[(size_t)i0 * 16 + c];
      float4 f1 = xh4[(size_t)i1 * 16 + c];
      float4 f2 = xh4[(size_t)i2 * 16 + c];
      float4 f3 = xh4[(size_t)i3 * 16 + c];
      PKACC(a, f0)
      PKACC(b, f1)
      PKACC(a, f2)
      PKACC(b, f3)
    }
    // small: 8 edges / iter (2 quads)
    for (; e + 8 <= end; e += 8) {
      int i0 = esrc[e + 0 + q];
      int i1 = esrc[e + 4 + q];
      float4 f0 = xh4[(size_t)i0 * 16 + c];
      float4 f1 = xh4[(size_t)i1 * 16 + c];
      PKACC(a, f0)
      PKACC(b, f1)
    }
    // final: predicated quad (esrc padded +8 ints -> idx read safe; data load
    // exec-masked for lanes with e+q >= end, so garbage idx is never used)
    for (; e < end; e += 4) {
      int i0 = esrc[e + q];
      if (e + q < end) {
        float4 f0 = xh4[(size_t)i0 * 16 + c];
        PKACC(a, f0)
      }
    }
    // merge dual accumulator sets
#pragma unroll
    for (int j = 0; j < 4; ++j) a[j] = __hadd2(a[j], b[j]);
    // widen to fp32 once per row
    float af[8];
    {
      float2 p0 = __half22float2(a[0]);
      float2 p1 = __half22float2(a[1]);
      float2 p2 = __half22float2(a[2]);
      float2 p3 = __half22float2(a[3]);
      af[0] = p0.x; af[1] = p0.y;
      af[2] = p1.x; af[3] = p1.y;
      af[4] = p2.x; af[5] = p2.y;
      af[6] = p3.x; af[7] = p3.y;
    }
    // combine quarters: lanes {c, c+16, c+32, c+48} hold partials of chunk c
#pragma unroll
    for (int j = 0; j < 8; ++j) {
      af[j] += __shfl_xor(af[j], 16);
      af[j] += __shfl_xor(af[j], 32);
    }
    // transposed store: feature f = c*8 + j; this lane writes j = 2q, 2q+1
    float w0 = QSEL(q, af[0], af[2], af[4], af[6]);
    float w1 = QSEL(q, af[1], af[3], af[5], af[7]);
    aT[(c * 8 + 2 * q + 0) * ATS + r] = w0;
    aT[(c * 8 + 2 * q + 1) * ATS + r] = w1;
  }
  __syncthreads();

  // ---- phase 2: GEMM 32x128 tile (fp32) ----
  int rg = lane >> 5;       // 0..1
  int cc = lane & 31;       // cols 4cc..4cc+3
  int rbase = w * 8 + rg * 4;

  float acc[4][4];
#pragma unroll
  for (int r = 0; r < 4; ++r)
#pragma unroll
    for (int j = 0; j < 4; ++j) acc[r][j] = 0.f;

#pragma unroll 4
  for (int k = 0; k < 128; ++k) {
    float4 bv = *(const float4*)(W + k * FDIM + cc * 4);
    float4 a0 = *(const float4*)(&aT[k * ATS + rbase]);
    float ar[4] = {a0.x, a0.y, a0.z, a0.w};
#pragma unroll
    for (int r = 0; r < 4; ++r) {
      acc[r][0] += ar[r] * bv.x;
      acc[r][1] += ar[r] * bv.y;
      acc[r][2] += ar[r] * bv.z;
      acc[r][3] += ar[r] * bv.w;
    }
  }

  float4 b4 = *(const float4*)(bias + cc * 4);

  if (POOL == 0) {
#pragma unroll
    for (int r = 0; r < 4; ++r) {
      int row = nodebase + rbase + r;
      if (row < NN) {
        float ox = fmaxf(acc[r][0] + b4.x, 0.f);
        float oy = fmaxf(acc[r][1] + b4.y, 0.f);
        float oz = fmaxf(acc[r][2] + b4.z, 0.f);
        float ow = fmaxf(acc[r][3] + b4.w, 0.f);
        union { uint2 u2; __half2 h[2]; } pk;
        pk.h[0] = __float22half2_rn(make_float2(ox, oy));
        pk.h[1] = __float22half2_rn(make_float2(oz, ow));
        *(uint2*)(out + (size_t)row * FDIM + cc * 4) = pk.u2;
      }
    }
  } else {
    // fused global_sum_pool (fp32): gl buffer UNIONS into aT -- all waves are
    // done reading aT (acc is in registers), but must barrier before overwrite.
    float* gl = aT;
    __syncthreads();
    if (t == 0) {
      sgv[0] = batching[nodebase];
      int last = nodebase + NPB - 1;
      if (last >= NN) last = NN - 1;
      sgv[1] = batching[last] - sgv[0] + 1;
    }
    for (int i = t; i < 8 * FDIM; i += 256) gl[i] = 0.f;
    __syncthreads();
    int g0 = sgv[0], nG = sgv[1];
    if (nG <= 8) {
#pragma unroll
      for (int r = 0; r < 4; ++r) {
        int row = nodebase + rbase + r;
        if (row < NN) {
          int slot = batching[row] - g0;
          atomicAdd(&gl[slot * FDIM + cc * 4 + 0], fmaxf(acc[r][0] + b4.x, 0.f));
          atomicAdd(&gl[slot * FDIM + cc * 4 + 1], fmaxf(acc[r][1] + b4.y, 0.f));
          atomicAdd(&gl[slot * FDIM + cc * 4 + 2], fmaxf(acc[r][2] + b4.z, 0.f));
          atomicAdd(&gl[slot * FDIM + cc * 4 + 3], fmaxf(acc[r][3] + b4.w, 0.f));
        }
      }
      __syncthreads();
      for (int i = t; i < nG * FDIM; i += 256) {
        float v = gl[i];
        if (v != 0.f)
          atomicAdd(&gout[(size_t)(g0 + (i >> 7)) * FDIM + (i & 127)], v);
      }
    } else {
#pragma unroll
      for (int r = 0; r < 4; ++r) {
        int row = nodebase + rbase + r;
        if (row < NN) {
          int gid = batching[row];
          atomicAdd(&gout[(size_t)gid * FDIM + cc * 4 + 0], fmaxf(acc[r][0] + b4.x, 0.f));
          atomicAdd(&gout[(size_t)gid * FDIM + cc * 4 + 1], fmaxf(acc[r][1] + b4.y, 0.f));
          atomicAdd(&gout[(size_t)gid * FDIM + cc * 4 + 2], fmaxf(acc[r][2] + b4.z, 0.f));
          atomicAdd(&gout[(size_t)gid * FDIM + cc * 4 + 3], fmaxf(acc[r][3] + b4.w, 0.f));
        }
      }
    }
  }
#undef PKACC
}

// ---------------- head: FC1 + FC2 + softmax over pooled g ----------------
__global__ __launch_bounds__(128) void head(const float* __restrict__ g,
                                            const float* __restrict__ Wf1,
                                            const float* __restrict__ bf1,
                                            const float* __restrict__ Wf2,
                                            const float* __restrict__ bf2,
                                            float* __restrict__ out) {
  __shared__ float gl[128];
  __shared__ float hl[64];
  __shared__ float ol[10];
  __shared__ float red[2];
  int gid = blockIdx.x, t = threadIdx.x;
  gl[t] = g[(size_t)gid * FDIM + t];
  __syncthreads();
  if (t < NFC1) {
    float h = bf1[t];
    for (int f = 0; f < 128; ++f) h += gl[f] * Wf1[f * NFC1 + t];
    hl[t] = h;
  }
  __syncthreads();
  if (t < NFC2) {
    float o = bf2[t];
    for (int i = 0; i < NFC1; ++i) o += hl[i] * Wf2[i * NFC2 + t];
    ol[t] = o;
  }
  __syncthreads();
  if (t == 0) {
    float m = ol[0];
    for (int i = 1; i < NFC2; ++i) m = fmaxf(m, ol[i]);
    float s = 0.f;
    for (int i = 0; i < NFC2; ++i) s += expf(ol[i] - m);
    red[0] = m;
    red[1] = s;
  }
  __syncthreads();
  if (t < NFC2) out[(size_t)gid * NFC2 + t] = expf(ol[t] - red[0]) / red[1];
}

extern "C" void kernel_launch(void* const* d_in, const int* in_sizes, int n_in,
                              void* d_out, int out_size, void* d_ws, size_t ws_size,
                              hipStream_t stream) {
  const float* node_attr = (const float*)d_in[0];
  const float* Wc = (const float*)d_in[1];   // [3][128][128]
  const float* bc = (const float*)d_in[2];   // [3][128]
  const float* Wf1 = (const float*)d_in[3];  // [128][64]
  const float* bf1 = (const float*)d_in[4];
  const float* Wf2 = (const float*)d_in[5];  // [64][10]
  const float* bf2 = (const float*)d_in[6];
  const int* src = (const int*)d_in[7];
  const int* dst = (const int*)d_in[8];
  const int* batching = (const int*)d_in[9];
  float* out = (float*)d_out;

  char* wsp = (char*)d_ws;
  size_t off = 0;
  auto alloc = [&](size_t bytes) -> void* {
    void* p = wsp + off;
    off += (bytes + 255) & ~(size_t)255;
    return p;
  };
  int* row_off = (int*)alloc((size_t)(NN + 1) * sizeof(int));
  int* gcursor = (int*)alloc(NBUCK * sizeof(int));
  int* esrc = (int*)alloc((size_t)(NE + 32) * sizeof(int));  // +32 pad for 8-quad over-read
  __half* xh0 = (__half*)alloc((size_t)NN * FDIM * sizeof(__half));   // 25.6 MB
  __half* bufA = (__half*)alloc((size_t)NN * FDIM * sizeof(__half));  // 25.6 MB
  __half* bufB = (__half*)alloc((size_t)NN * FDIM * sizeof(__half));  // 25.6 MB
  // staging (16.1 MB) aliases bufB: staging is dead (consumed by build_kernel)
  // before layer-2 writes bufB
  int* staging = (int*)bufB;
  // pooled g (512 KB fp32) aliases bufA: bufA dead after layer-2's gather;
  // memset enqueued after layer-2 launch (stream-ordered)
  float* gbuf = (float*)bufA;

  // CSR build via 2-level counting sort
  hipMemsetAsync(gcursor, 0, NBUCK * sizeof(int), stream);
  bin_kernel<<<(NE + 256 * EPB - 1) / (256 * EPB), 256, 0, stream>>>(src, dst, gcursor, staging);
  build_kernel<<<NBUCK, 256, 0, stream>>>(staging, gcursor, row_off, esrc);

  // node_attr fp32 -> fp16
  cvt_kernel<<<2048, 256, 0, stream>>>((const float4*)node_attr, (uint2*)xh0,
                                       NN * FDIM / 4);

  const int GRID = (NN + NPB - 1) / NPB;  // 3125

  // layer 1: bufA = fp16(relu(agg(xh0) @ W0 + b0))
  conv_fused<0><<<GRID, 256, 0, stream>>>((const float4*)xh0, row_off, esrc,
                                          Wc, bc, nullptr, bufA, nullptr);
  // layer 2: bufB = fp16(relu(agg(bufA) @ W1 + b1))
  conv_fused<0><<<GRID, 256, 0, stream>>>((const float4*)bufA, row_off, esrc,
                                          Wc + 16384, bc + 128, nullptr, bufB, nullptr);
  // layer 3 fused with global_sum_pool (fp32 epilogue, no x3 write)
  hipMemsetAsync(gbuf, 0, (size_t)NG * FDIM * sizeof(float), stream);
  conv_fused<1><<<GRID, 256, 0, stream>>>((const float4*)bufB, row_off, esrc,
                                          Wc + 32768, bc + 256, batching, nullptr, gbuf);

  // head
  head<<<NG, 128, 0, stream>>>(gbuf, Wf1, bf1, Wf2, bf2, out);
}

// Round 12
// 682.323 us; speedup vs baseline: 1.2660x; 1.0010x over previous
//
#include <hip/hip_runtime.h>
#include <hip/hip_fp16.h>
#include <math.h>

#define NN 100000
#define NE 3200000
#define NG 1024
#define FDIM 128
#define NFC1 64
#define NFC2 10

#define BSHIFT 9
#define NBUCK 196   // ceil(NN/512)
#define CAP 20480   // mean 16384, sigma ~127 -> 32-sigma headroom
#define EPB 16      // edges per thread in bin_kernel

#define NPB 32      // dst nodes per conv block (256 threads = 4 waves)
#define ATS 36      // aT leading-dim stride (32 + 4 pad)

#define RF __builtin_amdgcn_readfirstlane
// quarter-select: quarter q of the wave takes value k_q (static indices only)
#define QSEL(q, v0, v1, v2, v3) ((q) == 0 ? (v0) : (q) == 1 ? (v1) : (q) == 2 ? (v2) : (v3))

// ---------------- pass 1: bin edges into 196 coarse buckets ----------------
// Packed value: (dst & 511) << 17 | src   (src < 2^17, dst_local < 2^9)
__global__ __launch_bounds__(256) void bin_kernel(const int* __restrict__ src,
                                                  const int* __restrict__ dst,
                                                  int* __restrict__ gcursor,
                                                  int* __restrict__ staging) {
  __shared__ int hist[NBUCK];
  __shared__ int base[NBUCK];
  int t = threadIdx.x;
  for (int i = t; i < NBUCK; i += 256) hist[i] = 0;
  __syncthreads();
  size_t e0 = (size_t)blockIdx.x * (256 * EPB);
  int bk[EPB], rank[EPB], val[EPB];
#pragma unroll
  for (int j = 0; j < EPB; ++j) {
    size_t e = e0 + (size_t)j * 256 + t;
    if (e < NE) {
      int d = dst[e];
      int s = src[e];
      bk[j] = d >> BSHIFT;
      val[j] = ((d & 511) << 17) | s;
      rank[j] = atomicAdd(&hist[bk[j]], 1);
    } else {
      bk[j] = -1;
    }
  }
  __syncthreads();
  for (int i = t; i < NBUCK; i += 256) base[i] = atomicAdd(&gcursor[i], hist[i]);
  __syncthreads();
#pragma unroll
  for (int j = 0; j < EPB; ++j) {
    if (bk[j] >= 0) {
      int pos = base[bk[j]] + rank[j];
      if (pos < CAP) staging[(size_t)bk[j] * CAP + pos] = val[j];
    }
  }
}

// ---------------- pass 2: per-bucket CSR finalize (scan fused in) ----------------
__global__ __launch_bounds__(256) void build_kernel(const int* __restrict__ staging,
                                                    const int* __restrict__ gcursor,
                                                    int* __restrict__ row_off,
                                                    int* __restrict__ esrc) {
  __shared__ int ncnt[512];
  __shared__ int noff[513];
  __shared__ int part[256];
  __shared__ int sscan[256];
  int b = blockIdx.x, t = threadIdx.x;
  int gv = (t < NBUCK) ? gcursor[t] : 0;
  sscan[t] = gv;
  __syncthreads();
  for (int st = 1; st < 256; st <<= 1) {
    int u = (t >= st) ? sscan[t - st] : 0;
    __syncthreads();
    sscan[t] += u;
    __syncthreads();
  }
  int cnt = gcursor[b];
  int ebase = sscan[b] - cnt;  // exclusive prefix
  int nbase = b << BSHIFT;
  ncnt[t] = 0;
  ncnt[t + 256] = 0;
  __syncthreads();
  const int* sp = staging + (size_t)b * CAP;
  for (int i = t; i < cnt; i += 256) {
    int dl = sp[i] >> 17;
    atomicAdd(&ncnt[dl], 1);
  }
  __syncthreads();
  int a0 = ncnt[2 * t], a1 = ncnt[2 * t + 1];
  part[t] = a0 + a1;
  __syncthreads();
  for (int st = 1; st < 256; st <<= 1) {
    int u = (t >= st) ? part[t - st] : 0;
    __syncthreads();
    part[t] += u;
    __syncthreads();
  }
  int excl = (t > 0) ? part[t - 1] : 0;
  noff[2 * t] = excl;
  noff[2 * t + 1] = excl + a0;
  if (t == 255) noff[512] = part[255];
  __syncthreads();
  for (int i = t; i <= 512; i += 256) {
    int n = nbase + i;
    if (n <= NN) row_off[n] = ebase + noff[i];
  }
  // reuse ncnt as write cursors
  ncnt[2 * t] = noff[2 * t];
  ncnt[2 * t + 1] = noff[2 * t + 1];
  __syncthreads();
  for (int i = t; i < cnt; i += 256) {
    int v = sp[i];
    int dl = v >> 17;
    int pos = atomicAdd(&ncnt[dl], 1);
    esrc[ebase + pos] = v & 0x1FFFF;
  }
}

// ---------------- fp32 -> fp16 convert (node_attr -> xh0) ----------------
__global__ __launch_bounds__(256) void cvt_kernel(const float4* __restrict__ in,
                                                  uint2* __restrict__ outp, int n) {
  int i = blockIdx.x * 256 + threadIdx.x;
  int stride = gridDim.x * 256;
  for (; i < n; i += stride) {
    float4 v = in[i];
    union { __half2 h; unsigned u; } u0, u1;
    u0.h = __float22half2_rn(make_float2(v.x, v.y));
    u1.h = __float22half2_rn(make_float2(v.z, v.w));
    outp[i] = make_uint2(u0.u, u1.u);
  }
}

// ---------------- fused conv layer: out = relu(gather(xh)@W + bias) -------
// Gather path fp16 (row = 256B); GEMM/epilogue fp32.
// CHANGED this round: R11's 8-deep main loop never materialized -- the
// compiler regalloc'd to 32 VGPR by interleaving load/consume (depth ~2).
// A __builtin_amdgcn_sched_barrier(0) between the load loop and the consume
// loop FORCES all 8 idx + 8 dwordx4 loads to issue before any v_pk_add_f16
// (rule #18-adjacent: sched_barrier pins compile-time order). Expected
// VGPR ~60, genuine 128 B/lane in flight. Everything else identical to R11.
template <int POOL>
__global__ __launch_bounds__(256, 6) void conv_fused(const float4* __restrict__ xh4,
                                                     const int* __restrict__ row_off,
                                                     const int* __restrict__ esrc,
                                                     const float* __restrict__ W,
                                                     const float* __restrict__ bias,
                                                     const int* __restrict__ batching,
                                                     __half* __restrict__ out,
                                                     float* __restrict__ gout) {
  __shared__ __align__(16) float aT[128 * ATS];  // 18432 B; also reused as gl
  __shared__ int sgv[2];
  int t = threadIdx.x;
  int w = t >> 6;      // wave 0..3
  int lane = t & 63;
  int q = lane >> 4;   // edge within quad
  int c = lane & 15;   // 16B chunk within the 256B fp16 row
  int nodebase = blockIdx.x * NPB;

#define PKACC(A, fv)                                       \
  {                                                        \
    union { float4 f; __half2 h[4]; } u_;                  \
    u_.f = (fv);                                           \
    A[0] = __hadd2(A[0], u_.h[0]);                         \
    A[1] = __hadd2(A[1], u_.h[1]);                         \
    A[2] = __hadd2(A[2], u_.h[2]);                         \
    A[3] = __hadd2(A[3], u_.h[3]);                         \
  }

  // ---- phase 1: gather-aggregate 8 nodes for this wave ----
  for (int i = 0; i < 8; ++i) {
    int r = w * 8 + i;                  // 0..31
    int node = nodebase + r;
    int beg = 0, end = 0;
    if (node < NN) {
      beg = RF(row_off[node]);
      end = RF(row_off[node + 1]);
    }
    __half2 z = __float2half2_rn(0.f);
    __half2 a[4] = {z, z, z, z};
    __half2 b[4] = {z, z, z, z};
    int e = beg;
    // main: 32 edges / iter (8 quads). sched_barrier(0) forces all 8 data
    // loads in flight simultaneously (128 B/lane) before any consume.
    for (; e + 32 <= end; e += 32) {
      int ix[8];
#pragma unroll
      for (int g = 0; g < 8; ++g) ix[g] = esrc[e + 4 * g + q];
      float4 f[8];
#pragma unroll
      for (int g = 0; g < 8; ++g) f[g] = xh4[(size_t)ix[g] * 16 + c];
      __builtin_amdgcn_sched_barrier(0);  // no PKACC may move above this
#pragma unroll
      for (int g = 0; g < 8; g += 2) {
        PKACC(a, f[g])
        PKACC(b, f[g + 1])
      }
    }
    // mid: 16 edges / iter (4 quads)
    for (; e + 16 <= end; e += 16) {
      int i0 = esrc[e + 0 + q];
      int i1 = esrc[e + 4 + q];
      int i2 = esrc[e + 8 + q];
      int i3 = esrc[e + 12 + q];
      float4 f0 = xh4[(size_t)i0 * 16 + c];
      float4 f1 = xh4[(size_t)i1 * 16 + c];
      float4 f2 = xh4[(size_t)i2 * 16 + c];
      float4 f3 = xh4[(size_t)i3 * 16 + c];
      __builtin_amdgcn_sched_barrier(0);
      PKACC(a, f0)
      PKACC(b, f1)
      PKACC(a, f2)
      PKACC(b, f3)
    }
    // small: 8 edges / iter (2 quads)
    for (; e + 8 <= end; e += 8) {
      int i0 = esrc[e + 0 + q];
      int i1 = esrc[e + 4 + q];
      float4 f0 = xh4[(size_t)i0 * 16 + c];
      float4 f1 = xh4[(size_t)i1 * 16 + c];
      PKACC(a, f0)
      PKACC(b, f1)
    }
    // final: predicated quad (esrc padded +32 ints -> idx read safe; data load
    // exec-masked for lanes with e+q >= end, so garbage idx is never used)
    for (; e < end; e += 4) {
      int i0 = esrc[e + q];
      if (e + q < end) {
        float4 f0 = xh4[(size_t)i0 * 16 + c];
        PKACC(a, f0)
      }
    }
    // merge dual accumulator sets
#pragma unroll
    for (int j = 0; j < 4; ++j) a[j] = __hadd2(a[j], b[j]);
    // widen to fp32 once per row
    float af[8];
    {
      float2 p0 = __half22float2(a[0]);
      float2 p1 = __half22float2(a[1]);
      float2 p2 = __half22float2(a[2]);
      float2 p3 = __half22float2(a[3]);
      af[0] = p0.x; af[1] = p0.y;
      af[2] = p1.x; af[3] = p1.y;
      af[4] = p2.x; af[5] = p2.y;
      af[6] = p3.x; af[7] = p3.y;
    }
    // combine quarters: lanes {c, c+16, c+32, c+48} hold partials of chunk c
#pragma unroll
    for (int j = 0; j < 8; ++j) {
      af[j] += __shfl_xor(af[j], 16);
      af[j] += __shfl_xor(af[j], 32);
    }
    // transposed store: feature f = c*8 + j; this lane writes j = 2q, 2q+1
    float w0 = QSEL(q, af[0], af[2], af[4], af[6]);
    float w1 = QSEL(q, af[1], af[3], af[5], af[7]);
    aT[(c * 8 + 2 * q + 0) * ATS + r] = w0;
    aT[(c * 8 + 2 * q + 1) * ATS + r] = w1;
  }
  __syncthreads();

  // ---- phase 2: GEMM 32x128 tile (fp32) ----
  int rg = lane >> 5;       // 0..1
  int cc = lane & 31;       // cols 4cc..4cc+3
  int rbase = w * 8 + rg * 4;

  float acc[4][4];
#pragma unroll
  for (int r = 0; r < 4; ++r)
#pragma unroll
    for (int j = 0; j < 4; ++j) acc[r][j] = 0.f;

#pragma unroll 4
  for (int k = 0; k < 128; ++k) {
    float4 bv = *(const float4*)(W + k * FDIM + cc * 4);
    float4 a0 = *(const float4*)(&aT[k * ATS + rbase]);
    float ar[4] = {a0.x, a0.y, a0.z, a0.w};
#pragma unroll
    for (int r = 0; r < 4; ++r) {
      acc[r][0] += ar[r] * bv.x;
      acc[r][1] += ar[r] * bv.y;
      acc[r][2] += ar[r] * bv.z;
      acc[r][3] += ar[r] * bv.w;
    }
  }

  float4 b4 = *(const float4*)(bias + cc * 4);

  if (POOL == 0) {
#pragma unroll
    for (int r = 0; r < 4; ++r) {
      int row = nodebase + rbase + r;
      if (row < NN) {
        float ox = fmaxf(acc[r][0] + b4.x, 0.f);
        float oy = fmaxf(acc[r][1] + b4.y, 0.f);
        float oz = fmaxf(acc[r][2] + b4.z, 0.f);
        float ow = fmaxf(acc[r][3] + b4.w, 0.f);
        union { uint2 u2; __half2 h[2]; } pk;
        pk.h[0] = __float22half2_rn(make_float2(ox, oy));
        pk.h[1] = __float22half2_rn(make_float2(oz, ow));
        *(uint2*)(out + (size_t)row * FDIM + cc * 4) = pk.u2;
      }
    }
  } else {
    // fused global_sum_pool (fp32): gl buffer UNIONS into aT -- all waves are
    // done reading aT (acc is in registers), but must barrier before overwrite.
    float* gl = aT;
    __syncthreads();
    if (t == 0) {
      sgv[0] = batching[nodebase];
      int last = nodebase + NPB - 1;
      if (last >= NN) last = NN - 1;
      sgv[1] = batching[last] - sgv[0] + 1;
    }
    for (int i = t; i < 8 * FDIM; i += 256) gl[i] = 0.f;
    __syncthreads();
    int g0 = sgv[0], nG = sgv[1];
    if (nG <= 8) {
#pragma unroll
      for (int r = 0; r < 4; ++r) {
        int row = nodebase + rbase + r;
        if (row < NN) {
          int slot = batching[row] - g0;
          atomicAdd(&gl[slot * FDIM + cc * 4 + 0], fmaxf(acc[r][0] + b4.x, 0.f));
          atomicAdd(&gl[slot * FDIM + cc * 4 + 1], fmaxf(acc[r][1] + b4.y, 0.f));
          atomicAdd(&gl[slot * FDIM + cc * 4 + 2], fmaxf(acc[r][2] + b4.z, 0.f));
          atomicAdd(&gl[slot * FDIM + cc * 4 + 3], fmaxf(acc[r][3] + b4.w, 0.f));
        }
      }
      __syncthreads();
      for (int i = t; i < nG * FDIM; i += 256) {
        float v = gl[i];
        if (v != 0.f)
          atomicAdd(&gout[(size_t)(g0 + (i >> 7)) * FDIM + (i & 127)], v);
      }
    } else {
#pragma unroll
      for (int r = 0; r < 4; ++r) {
        int row = nodebase + rbase + r;
        if (row < NN) {
          int gid = batching[row];
          atomicAdd(&gout[(size_t)gid * FDIM + cc * 4 + 0], fmaxf(acc[r][0] + b4.x, 0.f));
          atomicAdd(&gout[(size_t)gid * FDIM + cc * 4 + 1], fmaxf(acc[r][1] + b4.y, 0.f));
          atomicAdd(&gout[(size_t)gid * FDIM + cc * 4 + 2], fmaxf(acc[r][2] + b4.z, 0.f));
          atomicAdd(&gout[(size_t)gid * FDIM + cc * 4 + 3], fmaxf(acc[r][3] + b4.w, 0.f));
        }
      }
    }
  }
#undef PKACC
}

// ---------------- head: FC1 + FC2 + softmax over pooled g ----------------
__global__ __launch_bounds__(128) void head(const float* __restrict__ g,
                                            const float* __restrict__ Wf1,
                                            const float* __restrict__ bf1,
                                            const float* __restrict__ Wf2,
                                            const float* __restrict__ bf2,
                                            float* __restrict__ out) {
  __shared__ float gl[128];
  __shared__ float hl[64];
  __shared__ float ol[10];
  __shared__ float red[2];
  int gid = blockIdx.x, t = threadIdx.x;
  gl[t] = g[(size_t)gid * FDIM + t];
  __syncthreads();
  if (t < NFC1) {
    float h = bf1[t];
    for (int f = 0; f < 128; ++f) h += gl[f] * Wf1[f * NFC1 + t];
    hl[t] = h;
  }
  __syncthreads();
  if (t < NFC2) {
    float o = bf2[t];
    for (int i = 0; i < NFC1; ++i) o += hl[i] * Wf2[i * NFC2 + t];
    ol[t] = o;
  }
  __syncthreads();
  if (t == 0) {
    float m = ol[0];
    for (int i = 1; i < NFC2; ++i) m = fmaxf(m, ol[i]);
    float s = 0.f;
    for (int i = 0; i < NFC2; ++i) s += expf(ol[i] - m);
    red[0] = m;
    red[1] = s;
  }
  __syncthreads();
  if (t < NFC2) out[(size_t)gid * NFC2 + t] = expf(ol[t] - red[0]) / red[1];
}

extern "C" void kernel_launch(void* const* d_in, const int* in_sizes, int n_in,
                              void* d_out, int out_size, void* d_ws, size_t ws_size,
                              hipStream_t stream) {
  const float* node_attr = (const float*)d_in[0];
  const float* Wc = (const float*)d_in[1];   // [3][128][128]
  const float* bc = (const float*)d_in[2];   // [3][128]
  const float* Wf1 = (const float*)d_in[3];  // [128][64]
  const float* bf1 = (const float*)d_in[4];
  const float* Wf2 = (const float*)d_in[5];  // [64][10]
  const float* bf2 = (const float*)d_in[6];
  const int* src = (const int*)d_in[7];
  const int* dst = (const int*)d_in[8];
  const int* batching = (const int*)d_in[9];
  float* out = (float*)d_out;

  char* wsp = (char*)d_ws;
  size_t off = 0;
  auto alloc = [&](size_t bytes) -> void* {
    void* p = wsp + off;
    off += (bytes + 255) & ~(size_t)255;
    return p;
  };
  int* row_off = (int*)alloc((size_t)(NN + 1) * sizeof(int));
  int* gcursor = (int*)alloc(NBUCK * sizeof(int));
  int* esrc = (int*)alloc((size_t)(NE + 32) * sizeof(int));  // +32 pad for 8-quad over-read
  __half* xh0 = (__half*)alloc((size_t)NN * FDIM * sizeof(__half));   // 25.6 MB
  __half* bufA = (__half*)alloc((size_t)NN * FDIM * sizeof(__half));  // 25.6 MB
  __half* bufB = (__half*)alloc((size_t)NN * FDIM * sizeof(__half));  // 25.6 MB
  // staging (16.1 MB) aliases bufB: staging is dead (consumed by build_kernel)
  // before layer-2 writes bufB
  int* staging = (int*)bufB;
  // pooled g (512 KB fp32) aliases bufA: bufA dead after layer-2's gather;
  // memset enqueued after layer-2 launch (stream-ordered)
  float* gbuf = (float*)bufA;

  // CSR build via 2-level counting sort
  hipMemsetAsync(gcursor, 0, NBUCK * sizeof(int), stream);
  bin_kernel<<<(NE + 256 * EPB - 1) / (256 * EPB), 256, 0, stream>>>(src, dst, gcursor, staging);
  build_kernel<<<NBUCK, 256, 0, stream>>>(staging, gcursor, row_off, esrc);

  // node_attr fp32 -> fp16
  cvt_kernel<<<2048, 256, 0, stream>>>((const float4*)node_attr, (uint2*)xh0,
                                       NN * FDIM / 4);

  const int GRID = (NN + NPB - 1) / NPB;  // 3125

  // layer 1: bufA = fp16(relu(agg(xh0) @ W0 + b0))
  conv_fused<0><<<GRID, 256, 0, stream>>>((const float4*)xh0, row_off, esrc,
                                          Wc, bc, nullptr, bufA, nullptr);
  // layer 2: bufB = fp16(relu(agg(bufA) @ W1 + b1))
  conv_fused<0><<<GRID, 256, 0, stream>>>((const float4*)bufA, row_off, esrc,
                                          Wc + 16384, bc + 128, nullptr, bufB, nullptr);
  // layer 3 fused with global_sum_pool (fp32 epilogue, no x3 write)
  hipMemsetAsync(gbuf, 0, (size_t)NG * FDIM * sizeof(float), stream);
  conv_fused<1><<<GRID, 256, 0, stream>>>((const float4*)bufB, row_off, esrc,
                                          Wc + 32768, bc + 256, batching, nullptr, gbuf);

  // head
  head<<<NG, 128, 0, stream>>>(gbuf, Wf1, bf1, Wf2, bf2, out);
}